// Round 3
// baseline (2466.379 us; speedup 1.0000x reference)
//
#include <hip/hip_runtime.h>
#include <stdint.h>

#define N_USERS 100000
#define N_NODES 150000
#define D0      128
#define H1      256
#define H2      128
#define NEDGE   4800000
#define BATCH   16384
#define EPSV    1e-5f

typedef short short8  __attribute__((ext_vector_type(8)));   // 8 bf16 (guide-verified MFMA frag type)
typedef float floatx4 __attribute__((ext_vector_type(4)));
typedef unsigned short u16;

__device__ inline float bf2f(u16 u) {
    union { float f; uint32_t i; } x; x.i = ((uint32_t)u) << 16; return x.f;
}
__device__ inline u16 f2bf(float f) {
    union { float f; uint32_t i; } x; x.f = f;
    return (u16)((x.i + 0x7FFFu + ((x.i >> 16) & 1u)) >> 16);  // RNE
}

// ---------------- utility ----------------
__global__ __launch_bounds__(256) void k_zero(int* __restrict__ p, int n) {
    int i = blockIdx.x * 256 + threadIdx.x;
    if (i < n) p[i] = 0;
}

__global__ __launch_bounds__(256) void k_fillf(float* __restrict__ p, int n, float v) {
    int i = blockIdx.x * 256 + threadIdx.x;
    if (i < n) p[i] = v;
}

// ---------------- CSR build ----------------
__global__ __launch_bounds__(256) void k_hist(const int* __restrict__ rows, int* __restrict__ cnt) {
    int i = blockIdx.x * 256 + threadIdx.x;
    if (i < NEDGE) atomicAdd(&cnt[rows[i]], 1);
}

// single-block (256 threads) exclusive scan of N_NODES counts
__global__ __launch_bounds__(256) void k_scan(const int* __restrict__ cnt,
                                              int* __restrict__ row_ptr,
                                              int* __restrict__ cursor) {
    const int T = 256;
    const int chunk = (N_NODES + T - 1) / T;  // 587
    int tid = threadIdx.x;
    int start = tid * chunk;
    int end = start + chunk;
    if (start > N_NODES) start = N_NODES;
    if (end > N_NODES) end = N_NODES;
    int local = 0;
    for (int i = start; i < end; ++i) local += cnt[i];
    int lane = tid & 63, wid = tid >> 6;
    int v = local;
    for (int off = 1; off < 64; off <<= 1) {
        int u = __shfl_up(v, off, 64);
        if (lane >= off) v += u;
    }
    __shared__ int wsum[4];
    if (lane == 63) wsum[wid] = v;
    __syncthreads();
    if (tid == 0) {
        int acc = 0;
        for (int w = 0; w < 4; ++w) { int t = wsum[w]; wsum[w] = acc; acc += t; }
    }
    __syncthreads();
    int run = (v - local) + wsum[wid];  // exclusive prefix of this thread's chunk
    for (int i = start; i < end; ++i) {
        row_ptr[i] = run; cursor[i] = run; run += cnt[i];
    }
    if (tid == T - 1) row_ptr[N_NODES] = run;
}

__global__ __launch_bounds__(256) void k_scatter(const int* __restrict__ rows,
                                                 const int* __restrict__ cols,
                                                 const float* __restrict__ vals,
                                                 int* __restrict__ cursor,
                                                 int* __restrict__ cols_s,
                                                 float* __restrict__ vals_s) {
    int i = blockIdx.x * 256 + threadIdx.x;
    if (i >= NEDGE) return;
    int r = rows[i];
    int pos = atomicAdd(&cursor[r], 1);
    cols_s[pos] = cols[i];
    vals_s[pos] = vals[i];
}

// ---------------- weight transpose fp32 -> bf16 ----------------
__global__ __launch_bounds__(256) void k_transpose(const float* __restrict__ W,
                                                   u16* __restrict__ WT, int K, int N) {
    int i = blockIdx.x * 256 + threadIdx.x;
    if (i >= K * N) return;
    int k = i / N, n = i - k * N;
    WT[n * K + k] = f2bf(W[i]);
}

// ---------------- MFMA GEMM (bf16 A): C[M,N] = A @ B + bias ----------------
// A bf16 row-major (split across Au/Ai at row `split`, multiple of 16); BT = B^T [N,K] bf16 rm.
// grid: (M/16, N/64), block 256 = 4 waves, one 16x16 n-tile per wave.
__global__ __launch_bounds__(256) void k_gemmB(const u16* __restrict__ Au,
                                               const u16* __restrict__ Ai, int split, int K,
                                               const u16* __restrict__ BT,
                                               const float* __restrict__ bias,
                                               u16* __restrict__ C, int N, int relu) {
    int lane = threadIdx.x & 63;
    int wid  = threadIdx.x >> 6;
    int m0 = blockIdx.x * 16;
    int n0 = blockIdx.y * 64 + wid * 16;
    const u16* A = (m0 < split) ? (Au + (size_t)m0 * K)
                                : (Ai + (size_t)(m0 - split) * K);
    int rn = lane & 15;          // A row (M) / B col (N) index within tile
    int kq = (lane >> 4) * 8;    // k offset within 32-wide k-chunk
    const u16* aptr = A + (size_t)rn * K + kq;
    const u16* bptr = BT + (size_t)(n0 + rn) * K + kq;
    floatx4 acc = {0.f, 0.f, 0.f, 0.f};
    for (int kt = 0; kt < K; kt += 32) {
        short8 a = *(const short8*)(const void*)(aptr + kt);
        short8 b = *(const short8*)(const void*)(bptr + kt);
        acc = __builtin_amdgcn_mfma_f32_16x16x32_bf16(a, b, acc, 0, 0, 0);
    }
    int col = n0 + rn;
    float bs = bias[col];
    int rbase = m0 + (lane >> 4) * 4;   // C/D: col=lane&15, row=(lane>>4)*4+i  [m89/m91]
    for (int i = 0; i < 4; ++i) {
        float v = acc[i] + bs;
        if (relu) v = v < 0.f ? 0.f : v;   // NaN-propagating relu
        C[(size_t)(rbase + i) * N + col] = f2bf(v);
    }
}

// ---------------- MFMA GEMM (fp32 A, converted in-register): layer 1 ----------------
__global__ __launch_bounds__(256) void k_gemmF(const float* __restrict__ Au,
                                               const float* __restrict__ Ai, int split, int K,
                                               const u16* __restrict__ BT,
                                               const float* __restrict__ bias,
                                               u16* __restrict__ C, int N) {
    int lane = threadIdx.x & 63;
    int wid  = threadIdx.x >> 6;
    int m0 = blockIdx.x * 16;
    int n0 = blockIdx.y * 64 + wid * 16;
    const float* A = (m0 < split) ? (Au + (size_t)m0 * K)
                                  : (Ai + (size_t)(m0 - split) * K);
    int rn = lane & 15;
    int kq = (lane >> 4) * 8;
    const float* aptr = A + (size_t)rn * K + kq;
    const u16*  bptr = BT + (size_t)(n0 + rn) * K + kq;
    floatx4 acc = {0.f, 0.f, 0.f, 0.f};
    for (int kt = 0; kt < K; kt += 32) {
        float4 f0 = *(const float4*)(const void*)(aptr + kt);
        float4 f1 = *(const float4*)(const void*)(aptr + kt + 4);
        short8 a;
        a[0] = (short)f2bf(f0.x); a[1] = (short)f2bf(f0.y);
        a[2] = (short)f2bf(f0.z); a[3] = (short)f2bf(f0.w);
        a[4] = (short)f2bf(f1.x); a[5] = (short)f2bf(f1.y);
        a[6] = (short)f2bf(f1.z); a[7] = (short)f2bf(f1.w);
        short8 b = *(const short8*)(const void*)(bptr + kt);
        acc = __builtin_amdgcn_mfma_f32_16x16x32_bf16(a, b, acc, 0, 0, 0);
    }
    int col = n0 + rn;
    float bs = bias[col];
    int rbase = m0 + (lane >> 4) * 4;
    for (int i = 0; i < 4; ++i) {
        C[(size_t)(rbase + i) * N + col] = f2bf(acc[i] + bs);
    }
}

// ---------------- aggregation: one wave per row ----------------
__global__ __launch_bounds__(256) void k_agg4(const u16* __restrict__ t,        // NF=256
                                              const int* __restrict__ row_ptr,
                                              const int* __restrict__ cols_s,
                                              const float* __restrict__ vals_s,
                                              u16* __restrict__ agg) {
    int row = blockIdx.x * 4 + (threadIdx.x >> 6);
    int lane = threadIdx.x & 63;
    if (row >= N_NODES) return;
    float a0 = 0.f, a1 = 0.f, a2 = 0.f, a3 = 0.f;
    int s = row_ptr[row], e = row_ptr[row + 1];
    for (int i = s; i < e; ++i) {
        int c = cols_s[i];
        float v = vals_s[i];
        const u16* p = t + (size_t)c * 256 + lane * 4;
        uint2 raw = *(const uint2*)(const void*)p;
        a0 += v * bf2f((u16)(raw.x & 0xffffu));
        a1 += v * bf2f((u16)(raw.x >> 16));
        a2 += v * bf2f((u16)(raw.y & 0xffffu));
        a3 += v * bf2f((u16)(raw.y >> 16));
    }
    uint2 w;
    w.x = (uint32_t)f2bf(a0) | ((uint32_t)f2bf(a1) << 16);
    w.y = (uint32_t)f2bf(a2) | ((uint32_t)f2bf(a3) << 16);
    *(uint2*)(void*)(agg + (size_t)row * 256 + lane * 4) = w;
}

__global__ __launch_bounds__(256) void k_agg2(const u16* __restrict__ t,        // NF=128
                                              const int* __restrict__ row_ptr,
                                              const int* __restrict__ cols_s,
                                              const float* __restrict__ vals_s,
                                              u16* __restrict__ agg) {
    int row = blockIdx.x * 4 + (threadIdx.x >> 6);
    int lane = threadIdx.x & 63;
    if (row >= N_NODES) return;
    float a0 = 0.f, a1 = 0.f;
    int s = row_ptr[row], e = row_ptr[row + 1];
    for (int i = s; i < e; ++i) {
        int c = cols_s[i];
        float v = vals_s[i];
        uint32_t raw = *(const uint32_t*)(const void*)(t + (size_t)c * 128 + lane * 2);
        a0 += v * bf2f((u16)(raw & 0xffffu));
        a1 += v * bf2f((u16)(raw >> 16));
    }
    uint32_t w = (uint32_t)f2bf(a0) | ((uint32_t)f2bf(a1) << 16);
    *(uint32_t*)(void*)(agg + (size_t)row * 128 + lane * 2) = w;
}

// ---------------- BatchNorm stats: stats[f]=sum, stats[NF+f]=sumsq ----------------
__global__ __launch_bounds__(256) void k_bnstats(const u16* __restrict__ agg,
                                                 float* __restrict__ stats, int NF) {
    int tid = threadIdx.x;
    int rpb = 256 / NF;                  // rows per block-iteration (1 or 2)
    int f = tid & (NF - 1);
    int r0 = blockIdx.x * rpb + tid / NF;
    int rs = gridDim.x * rpb;
    float s = 0.f, s2 = 0.f;
    for (int row = r0; row < N_NODES; row += rs) {
        float v = bf2f(agg[(size_t)row * NF + f]);
        s += v; s2 += v * v;
    }
    atomicAdd(&stats[f], s);
    atomicAdd(&stats[NF + f], s2);
}

// ---------------- BatchNorm apply + ReLU -> bf16 ----------------
__global__ __launch_bounds__(256) void k_bnapply(const u16* __restrict__ agg,
                                                 const float* __restrict__ stats,
                                                 const float* __restrict__ g,
                                                 const float* __restrict__ beta,
                                                 u16* __restrict__ x, int NF) {
    size_t idx = (size_t)blockIdx.x * 256 + threadIdx.x;
    if (idx >= (size_t)N_NODES * NF) return;
    int f = (int)(idx & (size_t)(NF - 1));
    float mu = stats[f] * (1.0f / N_NODES);
    float var = stats[NF + f] * (1.0f / N_NODES) - mu * mu;
    float sc = rsqrtf(var + EPSV) * g[f];
    float v = (bf2f(agg[idx]) - mu) * sc + beta[f];
    x[idx] = f2bf(v < 0.f ? 0.f : v);    // NaN-propagating relu (diagnosable, not masked)
}

// ---------------- gather u||v -> combined [B, 256] bf16 ----------------
__global__ __launch_bounds__(256) void k_gather(const int* __restrict__ ui, const int* __restrict__ ii,
                                                const u16* __restrict__ x2,
                                                u16* __restrict__ comb) {
    int item = blockIdx.x * 4 + (threadIdx.x >> 6);
    int lane = threadIdx.x & 63;
    if (item >= BATCH) return;
    const u16* src;
    if (lane < 32) src = x2 + (size_t)ui[item] * H2 + lane * 4;
    else           src = x2 + (size_t)(N_USERS + ii[item]) * H2 + (lane - 32) * 4;
    uint2 v = *(const uint2*)(const void*)src;
    *(uint2*)(void*)(comb + (size_t)item * (2 * H2) + lane * 4) = v;
}

// ---------------- final dot: pred = h @ P2 + pb2 (fp32 out) ----------------
__global__ __launch_bounds__(256) void k_final(const u16* __restrict__ h,
                                               const float* __restrict__ P2,
                                               const float* __restrict__ pb2,
                                               float* __restrict__ out) {
    int item = blockIdx.x * 4 + (threadIdx.x >> 6);
    int lane = threadIdx.x & 63;
    if (item >= BATCH) return;
    float a = bf2f(h[(size_t)item * H2 + lane])      * P2[lane]
            + bf2f(h[(size_t)item * H2 + 64 + lane]) * P2[64 + lane];
    for (int off = 32; off > 0; off >>= 1) a += __shfl_down(a, off, 64);
    if (lane == 0) out[item] = a + pb2[0];
}

extern "C" void kernel_launch(void* const* d_in, const int* in_sizes, int n_in,
                              void* d_out, int out_size, void* d_ws, size_t ws_size,
                              hipStream_t stream) {
    (void)in_sizes; (void)n_in; (void)ws_size;
    const int* user_indices = (const int*)d_in[0];
    const int* item_indices = (const int*)d_in[1];
    const int* edge_rows    = (const int*)d_in[2];
    const int* edge_cols    = (const int*)d_in[3];
    const float* edge_vals = (const float*)d_in[4];
    const float* user_emb  = (const float*)d_in[5];
    const float* item_emb  = (const float*)d_in[6];
    const float* W1    = (const float*)d_in[7];
    const float* b1    = (const float*)d_in[8];
    const float* g1    = (const float*)d_in[9];
    const float* beta1 = (const float*)d_in[10];
    const float* W2    = (const float*)d_in[11];
    const float* b2    = (const float*)d_in[12];
    const float* g2    = (const float*)d_in[13];
    const float* beta2 = (const float*)d_in[14];
    const float* P1    = (const float*)d_in[15];
    const float* pb1   = (const float*)d_in[16];
    const float* P2    = (const float*)d_in[17];
    const float* pb2   = (const float*)d_in[18];
    float* out = (float*)d_out;

    // workspace layout (~207 MB, 256B-aligned slots)
    char* ws = (char*)d_ws;
    size_t off = 0;
    auto alloc = [&](size_t bytes) -> char* {
        char* p = ws + off;
        off = (off + bytes + 255) & ~(size_t)255;
        return p;
    };
    int*   cnt     = (int*)alloc(sizeof(int) * N_NODES);
    int*   cursor  = (int*)alloc(sizeof(int) * N_NODES);
    int*   row_ptr = (int*)alloc(sizeof(int) * (N_NODES + 1));
    int*   cols_s  = (int*)alloc(sizeof(int) * NEDGE);
    float* vals_s  = (float*)alloc(sizeof(float) * NEDGE);
    u16* WT1 = (u16*)alloc(2 * D0 * H1);
    u16* WT2 = (u16*)alloc(2 * H1 * H2);
    u16* PT1 = (u16*)alloc(2 * 2 * H2 * H2);
    u16* A   = (u16*)alloc(2 * (size_t)N_NODES * H1);   // t1 -> x1 -> x2
    u16* B   = (u16*)alloc(2 * (size_t)N_NODES * H1);   // agg1 -> {agg2 | t2}
    u16* tB2 = B + (size_t)N_NODES * H2;                // layer-2 gemm output (upper half of B)
    float* stats1 = (float*)alloc(sizeof(float) * 2 * H1);
    float* stats2 = (float*)alloc(sizeof(float) * 2 * H2);
    u16* comb = (u16*)alloc(2 * (size_t)BATCH * 2 * H2);
    u16* hbuf = (u16*)alloc(2 * (size_t)BATCH * H2);

    // canary: 2.0f — on failure, absmax==max|ref| means launches no-op'd,
    // absmax==max|ref-2| means pipeline broke mid-way, NaN means numeric break
    k_fillf<<<(out_size + 255) / 256, 256, 0, stream>>>(out, out_size, 2.0f);

    // zero-init
    k_zero<<<(N_NODES + 255) / 256, 256, 0, stream>>>(cnt, N_NODES);
    k_zero<<<2, 256, 0, stream>>>((int*)stats1, 2 * H1);
    k_zero<<<1, 256, 0, stream>>>((int*)stats2, 2 * H2);

    // CSR build (reused by both layers)
    k_hist<<<(NEDGE + 255) / 256, 256, 0, stream>>>(edge_rows, cnt);
    k_scan<<<1, 256, 0, stream>>>(cnt, row_ptr, cursor);
    k_scatter<<<(NEDGE + 255) / 256, 256, 0, stream>>>(edge_rows, edge_cols, edge_vals,
                                                       cursor, cols_s, vals_s);
    // weight transpose + fp32->bf16 for MFMA B-operand
    k_transpose<<<(D0 * H1 + 255) / 256, 256, 0, stream>>>(W1, WT1, D0, H1);
    k_transpose<<<(H1 * H2 + 255) / 256, 256, 0, stream>>>(W2, WT2, H1, H2);
    k_transpose<<<(2 * H2 * H2 + 255) / 256, 256, 0, stream>>>(P1, PT1, 2 * H2, H2);

    // layer 1: t1 = [user_emb;item_emb] @ W1 + b1 ; agg ; BN+ReLU -> x1 (in A)
    k_gemmF<<<dim3(N_NODES / 16, H1 / 64), 256, 0, stream>>>(
        user_emb, item_emb, N_USERS, D0, WT1, b1, A, H1);
    k_agg4<<<N_NODES / 4, 256, 0, stream>>>(A, row_ptr, cols_s, vals_s, B);
    k_bnstats<<<512, 256, 0, stream>>>(B, stats1, H1);
    k_bnapply<<<(N_NODES * H1) / 256, 256, 0, stream>>>(B, stats1, g1, beta1, A, H1);

    // layer 2: t2 = x1 @ W2 + b2 (into tB2) ; agg (into B lo) ; BN+ReLU -> x2 (in A)
    k_gemmB<<<dim3(N_NODES / 16, H2 / 64), 256, 0, stream>>>(
        A, A, N_NODES, H1, WT2, b2, tB2, H2, 0);
    k_agg2<<<N_NODES / 4, 256, 0, stream>>>(tB2, row_ptr, cols_s, vals_s, B);
    k_bnstats<<<512, 256, 0, stream>>>(B, stats2, H2);
    k_bnapply<<<(N_NODES * H2) / 256, 256, 0, stream>>>(B, stats2, g2, beta2, A, H2);

    // prediction head
    k_gather<<<BATCH / 4, 256, 0, stream>>>(user_indices, item_indices, A, comb);
    k_gemmB<<<dim3(BATCH / 16, H2 / 64), 256, 0, stream>>>(
        comb, comb, BATCH, 2 * H2, PT1, pb1, hbuf, H2, 1);
    k_final<<<BATCH / 4, 256, 0, stream>>>(hbuf, P2, pb2, out);
}

// Round 4
// 1616.645 us; speedup vs baseline: 1.5256x; 1.5256x over previous
//
#include <hip/hip_runtime.h>
#include <stdint.h>

#define N_USERS 100000
#define N_NODES 150000
#define D0      128
#define H1      256
#define H2      128
#define NEDGE   4800000
#define BATCH   16384
#define EPSV    1e-5f

typedef short short8  __attribute__((ext_vector_type(8)));   // 8 bf16 MFMA frag
typedef float floatx4 __attribute__((ext_vector_type(4)));
typedef unsigned short u16;

__device__ inline float bf2f(u16 u) {
    union { float f; uint32_t i; } x; x.i = ((uint32_t)u) << 16; return x.f;
}
__device__ inline u16 f2bf(float f) {
    union { float f; uint32_t i; } x; x.f = f;
    return (u16)((x.i + 0x7FFFu + ((x.i >> 16) & 1u)) >> 16);  // RNE
}
__device__ inline float itof(uint32_t u) {
    union { float f; uint32_t i; } x; x.i = u; return x.f;
}
__device__ inline uint32_t ftoi(float f) {
    union { float f; uint32_t i; } x; x.f = f; return x.i;
}

// ---------------- utility ----------------
__global__ __launch_bounds__(256) void k_zero(int* __restrict__ p, int n) {
    int i = blockIdx.x * 256 + threadIdx.x;
    if (i < n) p[i] = 0;
}
__global__ __launch_bounds__(256) void k_fillf(float* __restrict__ p, int n, float v) {
    int i = blockIdx.x * 256 + threadIdx.x;
    if (i < n) p[i] = v;
}

// ---------------- x (fp32 user||item) -> bf16 xb ----------------
__global__ __launch_bounds__(256) void k_cvt(const float* __restrict__ ue,
                                             const float* __restrict__ ie,
                                             u16* __restrict__ xb) {
    int i = (blockIdx.x * 256 + threadIdx.x) * 4;
    const int NU = N_USERS * D0;
    const int NT = N_NODES * D0;
    if (i >= NT) return;
    const float* src = (i < NU) ? (ue + i) : (ie + (i - NU));
    float4 f = *(const float4*)(const void*)src;
    uint2 w;
    w.x = (uint32_t)f2bf(f.x) | ((uint32_t)f2bf(f.y) << 16);
    w.y = (uint32_t)f2bf(f.z) | ((uint32_t)f2bf(f.w) << 16);
    *(uint2*)(void*)(xb + i) = w;
}

// ---------------- CSR build ----------------
__global__ __launch_bounds__(256) void k_hist(const int* __restrict__ rows, int* __restrict__ cnt) {
    int i = blockIdx.x * 256 + threadIdx.x;
    if (i < NEDGE) atomicAdd(&cnt[rows[i]], 1);
}

// 3-phase parallel exclusive scan of cnt[N_NODES]
__global__ __launch_bounds__(256) void k_scan1(const int* __restrict__ cnt, int* __restrict__ bsum) {
    __shared__ int wsum[4];
    int idx = blockIdx.x * 256 + threadIdx.x;
    int v = (idx < N_NODES) ? cnt[idx] : 0;
    int lane = threadIdx.x & 63, wid = threadIdx.x >> 6;
    for (int off = 32; off > 0; off >>= 1) v += __shfl_down(v, off, 64);
    if (lane == 0) wsum[wid] = v;
    __syncthreads();
    if (threadIdx.x == 0) bsum[blockIdx.x] = wsum[0] + wsum[1] + wsum[2] + wsum[3];
}

__global__ __launch_bounds__(256) void k_scan2(int* __restrict__ bsum, int* __restrict__ row_ptr) {
    const int NB = (N_NODES + 255) / 256;   // 586
    const int C  = (NB + 255) / 256;        // 3
    int tid = threadIdx.x;
    int start = tid * C, end = start + C;
    if (start > NB) start = NB;
    if (end > NB) end = NB;
    int local = 0;
    for (int i = start; i < end; ++i) local += bsum[i];
    int lane = tid & 63, wid = tid >> 6;
    int v = local;
    for (int off = 1; off < 64; off <<= 1) {
        int u = __shfl_up(v, off, 64);
        if (lane >= off) v += u;
    }
    __shared__ int wsum[4];
    if (lane == 63) wsum[wid] = v;
    __syncthreads();
    int base = 0;
    for (int w = 0; w < wid; ++w) base += wsum[w];
    int run = base + (v - local);
    for (int i = start; i < end; ++i) { int t = bsum[i]; bsum[i] = run; run += t; }
    if (tid == 255) row_ptr[N_NODES] = run;   // total
}

__global__ __launch_bounds__(256) void k_scan3(const int* __restrict__ cnt,
                                               const int* __restrict__ bsum,
                                               int* __restrict__ row_ptr,
                                               int* __restrict__ cursor) {
    int idx = blockIdx.x * 256 + threadIdx.x;
    int c = (idx < N_NODES) ? cnt[idx] : 0;
    int lane = threadIdx.x & 63, wid = threadIdx.x >> 6;
    int v = c;
    for (int off = 1; off < 64; off <<= 1) {
        int u = __shfl_up(v, off, 64);
        if (lane >= off) v += u;
    }
    __shared__ int wsum[4];
    if (lane == 63) wsum[wid] = v;
    __syncthreads();
    int base = bsum[blockIdx.x];
    for (int w = 0; w < wid; ++w) base += wsum[w];
    int ex = base + v - c;
    if (idx < N_NODES) { row_ptr[idx] = ex; cursor[idx] = ex; }
}

// packed (col, val_bits) per edge, one 8 B scattered store
__global__ __launch_bounds__(256) void k_scatter(const int* __restrict__ rows,
                                                 const int* __restrict__ cols,
                                                 const float* __restrict__ vals,
                                                 int* __restrict__ cursor,
                                                 uint2* __restrict__ edges) {
    int i = blockIdx.x * 256 + threadIdx.x;
    if (i >= NEDGE) return;
    int r = rows[i];
    int pos = atomicAdd(&cursor[r], 1);
    uint2 e; e.x = (uint32_t)cols[i]; e.y = ftoi(vals[i]);
    edges[pos] = e;
}

// ---------------- weight transpose fp32 -> bf16 ----------------
__global__ __launch_bounds__(256) void k_transpose(const float* __restrict__ W,
                                                   u16* __restrict__ WT, int K, int N) {
    int i = blockIdx.x * 256 + threadIdx.x;
    if (i >= K * N) return;
    int k = i / N, n = i - k * N;
    WT[n * K + k] = f2bf(W[i]);
}

// ---------------- MFMA GEMM: C[M,N] = A[M,K] @ B[K,N] + rs*bias ----------------
// A bf16 rm; BT = B^T [N,K] bf16 rm; rowscale optional (layer-1 s_r); relu flag.
// grid: (M/16, N/64), block 256 = 4 waves, one 16x16 n-tile per wave.
__global__ __launch_bounds__(256) void k_gemm(const u16* __restrict__ A, int K,
                                              const u16* __restrict__ BT,
                                              const float* __restrict__ bias,
                                              const float* __restrict__ rowscale,
                                              u16* __restrict__ C, int N, int relu) {
    int lane = threadIdx.x & 63;
    int wid  = threadIdx.x >> 6;
    int m0 = blockIdx.x * 16;
    int n0 = blockIdx.y * 64 + wid * 16;
    int rn = lane & 15;          // A row (M) / B col (N) within tile
    int kq = (lane >> 4) * 8;    // k offset within 32-wide k-chunk
    const u16* aptr = A  + (size_t)(m0 + rn) * K + kq;
    const u16* bptr = BT + (size_t)(n0 + rn) * K + kq;
    floatx4 acc = {0.f, 0.f, 0.f, 0.f};
    for (int kt = 0; kt < K; kt += 32) {
        short8 a = *(const short8*)(const void*)(aptr + kt);
        short8 b = *(const short8*)(const void*)(bptr + kt);
        acc = __builtin_amdgcn_mfma_f32_16x16x32_bf16(a, b, acc, 0, 0, 0);
    }
    int col = n0 + rn;
    float bs = bias[col];
    int rbase = m0 + (lane >> 4) * 4;   // C/D: col=lane&15, row=(lane>>4)*4+i
    for (int i = 0; i < 4; ++i) {
        float rs = rowscale ? rowscale[rbase + i] : 1.0f;
        float v = acc[i] + rs * bs;
        if (relu) v = v < 0.f ? 0.f : v;   // NaN-propagating
        C[(size_t)(rbase + i) * N + col] = f2bf(v);
    }
}

// ---------------- aggregation (NF=128): one wave per row, 4-deep pipelined ----------------
__global__ __launch_bounds__(256) void k_agg(const u16* __restrict__ t,
                                             const int* __restrict__ row_ptr,
                                             const uint2* __restrict__ edges,
                                             u16* __restrict__ agg,
                                             float* __restrict__ rowsum) {
    int row = blockIdx.x * 4 + (threadIdx.x >> 6);
    int lane = threadIdx.x & 63;
    if (row >= N_NODES) return;
    float a0 = 0.f, a1 = 0.f, sv = 0.f;
    int s = row_ptr[row], e = row_ptr[row + 1];
    int i = s;
    for (; i + 4 <= e; i += 4) {
        uint2 e0 = edges[i], e1 = edges[i + 1], e2 = edges[i + 2], e3 = edges[i + 3];
        uint32_t r0 = *(const uint32_t*)(const void*)(t + (size_t)e0.x * 128 + lane * 2);
        uint32_t r1 = *(const uint32_t*)(const void*)(t + (size_t)e1.x * 128 + lane * 2);
        uint32_t r2 = *(const uint32_t*)(const void*)(t + (size_t)e2.x * 128 + lane * 2);
        uint32_t r3 = *(const uint32_t*)(const void*)(t + (size_t)e3.x * 128 + lane * 2);
        float v0 = itof(e0.y), v1 = itof(e1.y), v2 = itof(e2.y), v3 = itof(e3.y);
        a0 += v0 * bf2f((u16)(r0 & 0xffffu)); a1 += v0 * bf2f((u16)(r0 >> 16));
        a0 += v1 * bf2f((u16)(r1 & 0xffffu)); a1 += v1 * bf2f((u16)(r1 >> 16));
        a0 += v2 * bf2f((u16)(r2 & 0xffffu)); a1 += v2 * bf2f((u16)(r2 >> 16));
        a0 += v3 * bf2f((u16)(r3 & 0xffffu)); a1 += v3 * bf2f((u16)(r3 >> 16));
        sv += v0 + v1 + v2 + v3;
    }
    for (; i < e; ++i) {
        uint2 e0 = edges[i];
        uint32_t r0 = *(const uint32_t*)(const void*)(t + (size_t)e0.x * 128 + lane * 2);
        float v0 = itof(e0.y);
        a0 += v0 * bf2f((u16)(r0 & 0xffffu)); a1 += v0 * bf2f((u16)(r0 >> 16));
        sv += v0;
    }
    uint32_t w = (uint32_t)f2bf(a0) | ((uint32_t)f2bf(a1) << 16);
    *(uint32_t*)(void*)(agg + (size_t)row * 128 + lane * 2) = w;
    if (rowsum != nullptr && lane == 0) rowsum[row] = sv;
}

// ---------------- BatchNorm stats: stats[f]=sum, stats[NF+f]=sumsq ----------------
__global__ __launch_bounds__(256) void k_bnstats(const u16* __restrict__ agg,
                                                 float* __restrict__ stats, int NF) {
    int tid = threadIdx.x;
    int rpb = 256 / NF;
    int f = tid & (NF - 1);
    int r0 = blockIdx.x * rpb + tid / NF;
    int rs = gridDim.x * rpb;
    float s = 0.f, s2 = 0.f;
    for (int row = r0; row < N_NODES; row += rs) {
        float v = bf2f(agg[(size_t)row * NF + f]);
        s += v; s2 += v * v;
    }
    atomicAdd(&stats[f], s);
    atomicAdd(&stats[NF + f], s2);
}

// ---------------- BatchNorm apply + ReLU -> bf16 ----------------
__global__ __launch_bounds__(256) void k_bnapply(const u16* __restrict__ agg,
                                                 const float* __restrict__ stats,
                                                 const float* __restrict__ g,
                                                 const float* __restrict__ beta,
                                                 u16* __restrict__ x, int NF) {
    size_t idx = (size_t)blockIdx.x * 256 + threadIdx.x;
    if (idx >= (size_t)N_NODES * NF) return;
    int f = (int)(idx & (size_t)(NF - 1));
    float mu = stats[f] * (1.0f / N_NODES);
    float var = stats[NF + f] * (1.0f / N_NODES) - mu * mu;
    float sc = rsqrtf(var + EPSV) * g[f];
    float v = (bf2f(agg[idx]) - mu) * sc + beta[f];
    x[idx] = f2bf(v < 0.f ? 0.f : v);
}

// ---------------- gather u||v with fused BN2+ReLU -> comb [B,256] bf16 ----------------
__global__ __launch_bounds__(256) void k_gatherBN(const int* __restrict__ ui,
                                                  const int* __restrict__ ii,
                                                  const u16* __restrict__ agg2,
                                                  const float* __restrict__ stats,
                                                  const float* __restrict__ g,
                                                  const float* __restrict__ beta,
                                                  u16* __restrict__ comb) {
    int item = blockIdx.x * 4 + (threadIdx.x >> 6);
    int lane = threadIdx.x & 63;
    if (item >= BATCH) return;
    int node = (lane < 32) ? ui[item] : (N_USERS + ii[item]);
    int fb = (lane & 31) * 4;
    uint2 r = *(const uint2*)(const void*)(agg2 + (size_t)node * H2 + fb);
    float vv[4] = { bf2f((u16)(r.x & 0xffffu)), bf2f((u16)(r.x >> 16)),
                    bf2f((u16)(r.y & 0xffffu)), bf2f((u16)(r.y >> 16)) };
    u16 o[4];
    for (int j = 0; j < 4; ++j) {
        int f = fb + j;
        float mu = stats[f] * (1.0f / N_NODES);
        float var = stats[H2 + f] * (1.0f / N_NODES) - mu * mu;
        float sc = rsqrtf(var + EPSV) * g[f];
        float v = (vv[j] - mu) * sc + beta[f];
        o[j] = f2bf(v < 0.f ? 0.f : v);
    }
    uint2 w;
    w.x = (uint32_t)o[0] | ((uint32_t)o[1] << 16);
    w.y = (uint32_t)o[2] | ((uint32_t)o[3] << 16);
    *(uint2*)(void*)(comb + (size_t)item * (2 * H2) + lane * 4) = w;
}

// ---------------- final dot: pred = h @ P2 + pb2 (fp32 out) ----------------
__global__ __launch_bounds__(256) void k_final(const u16* __restrict__ h,
                                               const float* __restrict__ P2,
                                               const float* __restrict__ pb2,
                                               float* __restrict__ out) {
    int item = blockIdx.x * 4 + (threadIdx.x >> 6);
    int lane = threadIdx.x & 63;
    if (item >= BATCH) return;
    float a = bf2f(h[(size_t)item * H2 + lane])      * P2[lane]
            + bf2f(h[(size_t)item * H2 + 64 + lane]) * P2[64 + lane];
    for (int off = 32; off > 0; off >>= 1) a += __shfl_down(a, off, 64);
    if (lane == 0) out[item] = a + pb2[0];
}

extern "C" void kernel_launch(void* const* d_in, const int* in_sizes, int n_in,
                              void* d_out, int out_size, void* d_ws, size_t ws_size,
                              hipStream_t stream) {
    (void)in_sizes; (void)n_in; (void)ws_size;
    const int* user_indices = (const int*)d_in[0];
    const int* item_indices = (const int*)d_in[1];
    const int* edge_rows    = (const int*)d_in[2];
    const int* edge_cols    = (const int*)d_in[3];
    const float* edge_vals = (const float*)d_in[4];
    const float* user_emb  = (const float*)d_in[5];
    const float* item_emb  = (const float*)d_in[6];
    const float* W1    = (const float*)d_in[7];
    const float* b1    = (const float*)d_in[8];
    const float* g1    = (const float*)d_in[9];
    const float* beta1 = (const float*)d_in[10];
    const float* W2    = (const float*)d_in[11];
    const float* b2    = (const float*)d_in[12];
    const float* g2    = (const float*)d_in[13];
    const float* beta2 = (const float*)d_in[14];
    const float* P1    = (const float*)d_in[15];
    const float* pb1   = (const float*)d_in[16];
    const float* P2    = (const float*)d_in[17];
    const float* pb2   = (const float*)d_in[18];
    float* out = (float*)d_out;

    // workspace layout (~195 MB)
    char* ws = (char*)d_ws;
    size_t off = 0;
    auto alloc = [&](size_t bytes) -> char* {
        char* p = ws + off;
        off = (off + bytes + 255) & ~(size_t)255;
        return p;
    };
    int*   cnt     = (int*)alloc(sizeof(int) * N_NODES);
    int*   cursor  = (int*)alloc(sizeof(int) * N_NODES);
    int*   row_ptr = (int*)alloc(sizeof(int) * (N_NODES + 1));
    int*   bsum    = (int*)alloc(sizeof(int) * 1024);
    float* rowsum  = (float*)alloc(sizeof(float) * N_NODES);
    float* stats1  = (float*)alloc(sizeof(float) * 2 * H1);
    float* stats2  = (float*)alloc(sizeof(float) * 2 * H2);
    u16* WT1 = (u16*)alloc(2 * D0 * H1);
    u16* WT2 = (u16*)alloc(2 * H1 * H2);
    u16* PT1 = (u16*)alloc(2 * 2 * H2 * H2);
    uint2* edges = (uint2*)alloc(8 * (size_t)NEDGE);
    // R1 (76.8 MB): xb | aggx, later x1 (full)
    u16* R1   = (u16*)alloc(2 * (size_t)N_NODES * H1);
    u16* xb   = R1;
    u16* aggx = R1 + (size_t)N_NODES * D0;
    u16* x1   = R1;
    // R2 (76.8 MB): agg1, later t2 | agg2, later comb+hbuf | agg2
    u16* R2   = (u16*)alloc(2 * (size_t)N_NODES * H1);
    u16* agg1 = R2;
    u16* t2   = R2;
    u16* agg2 = R2 + (size_t)N_NODES * H2;
    u16* comb = R2;
    u16* hbuf = R2 + (size_t)BATCH * 2 * H2;

    // canary (distinguish failure modes)
    k_fillf<<<(out_size + 255) / 256, 256, 0, stream>>>(out, out_size, 2.0f);

    // zero-init
    k_zero<<<(N_NODES + 255) / 256, 256, 0, stream>>>(cnt, N_NODES);
    k_zero<<<2, 256, 0, stream>>>((int*)stats1, 2 * H1);
    k_zero<<<1, 256, 0, stream>>>((int*)stats2, 2 * H2);

    // x -> bf16
    k_cvt<<<(N_NODES * D0 / 4 + 255) / 256, 256, 0, stream>>>(user_emb, item_emb, xb);

    // CSR build
    k_hist<<<(NEDGE + 255) / 256, 256, 0, stream>>>(edge_rows, cnt);
    k_scan1<<<(N_NODES + 255) / 256, 256, 0, stream>>>(cnt, bsum);
    k_scan2<<<1, 256, 0, stream>>>(bsum, row_ptr);
    k_scan3<<<(N_NODES + 255) / 256, 256, 0, stream>>>(cnt, bsum, row_ptr, cursor);
    k_scatter<<<(NEDGE + 255) / 256, 256, 0, stream>>>(edge_rows, edge_cols, edge_vals,
                                                       cursor, edges);

    // weight transposes fp32 -> bf16 (B^T layout)
    k_transpose<<<(D0 * H1 + 255) / 256, 256, 0, stream>>>(W1, WT1, D0, H1);
    k_transpose<<<(H1 * H2 + 255) / 256, 256, 0, stream>>>(W2, WT2, H1, H2);
    k_transpose<<<(2 * H2 * H2 + 255) / 256, 256, 0, stream>>>(P1, PT1, 2 * H2, H2);

    // layer 1 (agg-then-GEMM via linearity): aggx = agg(xb), s_r; agg1 = aggx@W1 + s_r*b1
    k_agg<<<N_NODES / 4, 256, 0, stream>>>(xb, row_ptr, edges, aggx, rowsum);
    k_gemm<<<dim3(N_NODES / 16, H1 / 64), 256, 0, stream>>>(
        aggx, D0, WT1, b1, rowsum, agg1, H1, 0);
    k_bnstats<<<512, 256, 0, stream>>>(agg1, stats1, H1);
    k_bnapply<<<(N_NODES * H1) / 256, 256, 0, stream>>>(agg1, stats1, g1, beta1, x1, H1);

    // layer 2 (GEMM-then-agg): t2 = x1@W2 + b2 ; agg2 = agg(t2)
    k_gemm<<<dim3(N_NODES / 16, H2 / 64), 256, 0, stream>>>(
        x1, H1, WT2, b2, nullptr, t2, H2, 0);
    k_agg<<<N_NODES / 4, 256, 0, stream>>>(t2, row_ptr, edges, agg2, nullptr);
    k_bnstats<<<512, 256, 0, stream>>>(agg2, stats2, H2);

    // head: gather with fused BN2+ReLU, MLP, dot
    k_gatherBN<<<BATCH / 4, 256, 0, stream>>>(user_indices, item_indices, agg2,
                                              stats2, g2, beta2, comb);
    k_gemm<<<dim3(BATCH / 16, H2 / 64), 256, 0, stream>>>(
        comb, 2 * H2, PT1, pb1, nullptr, hbuf, H2, 1);
    k_final<<<BATCH / 4, 256, 0, stream>>>(hbuf, P2, pb2, out);
}

// Round 5
// 1196.075 us; speedup vs baseline: 2.0621x; 1.3516x over previous
//
#include <hip/hip_runtime.h>
#include <stdint.h>

#define N_USERS 100000
#define N_NODES 150000
#define D0      128
#define H1      256
#define H2      128
#define NEDGE   4800000
#define BATCH   16384
#define EPSV    1e-5f
#define NBUCK   147          // ceil(150000/1024) coarse buckets (1024 rows each)
#define BCHUNK  4096         // edges per k_bucket block

typedef short short8  __attribute__((ext_vector_type(8)));   // 8 bf16 MFMA frag
typedef float floatx4 __attribute__((ext_vector_type(4)));
typedef unsigned short u16;

__device__ inline float bf2f(u16 u) {
    union { float f; uint32_t i; } x; x.i = ((uint32_t)u) << 16; return x.f;
}
__device__ inline u16 f2bf(float f) {
    union { float f; uint32_t i; } x; x.f = f;
    return (u16)((x.i + 0x7FFFu + ((x.i >> 16) & 1u)) >> 16);  // RNE
}
__device__ inline float itof(uint32_t u) {
    union { float f; uint32_t i; } x; x.i = u; return x.f;
}
__device__ inline uint32_t ftoi(float f) {
    union { float f; uint32_t i; } x; x.f = f; return x.i;
}

// ---------------- utility ----------------
__global__ __launch_bounds__(256) void k_zero(int* __restrict__ p, int n) {
    int i = blockIdx.x * 256 + threadIdx.x;
    if (i < n) p[i] = 0;
}
__global__ __launch_bounds__(256) void k_fillf(float* __restrict__ p, int n, float v) {
    int i = blockIdx.x * 256 + threadIdx.x;
    if (i < n) p[i] = v;
}

// ---------------- x (fp32 user||item) -> bf16 xb ----------------
__global__ __launch_bounds__(256) void k_cvt(const float* __restrict__ ue,
                                             const float* __restrict__ ie,
                                             u16* __restrict__ xb) {
    int i = (blockIdx.x * 256 + threadIdx.x) * 4;
    const int NU = N_USERS * D0;
    const int NT = N_NODES * D0;
    if (i >= NT) return;
    const float* src = (i < NU) ? (ue + i) : (ie + (i - NU));
    float4 f = *(const float4*)(const void*)src;
    uint2 w;
    w.x = (uint32_t)f2bf(f.x) | ((uint32_t)f2bf(f.y) << 16);
    w.y = (uint32_t)f2bf(f.z) | ((uint32_t)f2bf(f.w) << 16);
    *(uint2*)(void*)(xb + i) = w;
}

// ---------------- CSR build: histogram + 3-phase scan ----------------
__global__ __launch_bounds__(256) void k_hist(const int* __restrict__ rows, int* __restrict__ cnt) {
    int i = blockIdx.x * 256 + threadIdx.x;
    if (i < NEDGE) atomicAdd(&cnt[rows[i]], 1);
}

__global__ __launch_bounds__(256) void k_scan1(const int* __restrict__ cnt, int* __restrict__ bsum) {
    __shared__ int wsum[4];
    int idx = blockIdx.x * 256 + threadIdx.x;
    int v = (idx < N_NODES) ? cnt[idx] : 0;
    int lane = threadIdx.x & 63, wid = threadIdx.x >> 6;
    for (int off = 32; off > 0; off >>= 1) v += __shfl_down(v, off, 64);
    if (lane == 0) wsum[wid] = v;
    __syncthreads();
    if (threadIdx.x == 0) bsum[blockIdx.x] = wsum[0] + wsum[1] + wsum[2] + wsum[3];
}

__global__ __launch_bounds__(256) void k_scan2(int* __restrict__ bsum, int* __restrict__ row_ptr) {
    const int NB = (N_NODES + 255) / 256;   // 586
    const int C  = (NB + 255) / 256;        // 3
    int tid = threadIdx.x;
    int start = tid * C, end = start + C;
    if (start > NB) start = NB;
    if (end > NB) end = NB;
    int local = 0;
    for (int i = start; i < end; ++i) local += bsum[i];
    int lane = tid & 63, wid = tid >> 6;
    int v = local;
    for (int off = 1; off < 64; off <<= 1) {
        int u = __shfl_up(v, off, 64);
        if (lane >= off) v += u;
    }
    __shared__ int wsum[4];
    if (lane == 63) wsum[wid] = v;
    __syncthreads();
    int base = 0;
    for (int w = 0; w < wid; ++w) base += wsum[w];
    int run = base + (v - local);
    for (int i = start; i < end; ++i) { int t = bsum[i]; bsum[i] = run; run += t; }
    if (tid == 255) row_ptr[N_NODES] = run;
}

__global__ __launch_bounds__(256) void k_scan3(const int* __restrict__ cnt,
                                               const int* __restrict__ bsum,
                                               int* __restrict__ row_ptr) {
    int idx = blockIdx.x * 256 + threadIdx.x;
    int c = (idx < N_NODES) ? cnt[idx] : 0;
    int lane = threadIdx.x & 63, wid = threadIdx.x >> 6;
    int v = c;
    for (int off = 1; off < 64; off <<= 1) {
        int u = __shfl_up(v, off, 64);
        if (lane >= off) v += u;
    }
    __shared__ int wsum[4];
    if (lane == 63) wsum[wid] = v;
    __syncthreads();
    int base = bsum[blockIdx.x];
    for (int w = 0; w < wid; ++w) base += wsum[w];
    if (idx < N_NODES) row_ptr[idx] = base + v - c;
}

__global__ __launch_bounds__(256) void k_binit(const int* __restrict__ row_ptr,
                                               int* __restrict__ bucket_cursor) {
    int b = threadIdx.x;
    if (b < NBUCK) bucket_cursor[b] = row_ptr[b << 10];
}

// ---------------- pass 1: LDS-staged bucket append (coalesced spans) ----------------
// payload packed: x = (rowlocal<<18) | col, y = val bits
__global__ __launch_bounds__(256) void k_bucket(const int* __restrict__ rows,
                                                const int* __restrict__ cols,
                                                const float* __restrict__ vals,
                                                int* __restrict__ bucket_cursor,
                                                uint2* __restrict__ etmp) {
    __shared__ uint2 stage[BCHUNK];        // 32 KB
    __shared__ u16   slotb[BCHUNK];        // 8 KB
    __shared__ int   lcnt[NBUCK + 1];
    __shared__ int   lscan[NBUCK + 1];
    __shared__ int   gstart[NBUCK];
    int tid = threadIdx.x;
    int e0 = blockIdx.x * BCHUNK;
    int nE = NEDGE - e0; if (nE > BCHUNK) nE = BCHUNK;

    for (int i = tid; i <= NBUCK; i += 256) lcnt[i] = 0;
    __syncthreads();
    // count
    for (int i = tid; i < nE; i += 256) atomicAdd(&lcnt[rows[e0 + i] >> 10], 1);
    __syncthreads();
    // reserve global spans (one atomic per bucket per block)
    if (tid < NBUCK) gstart[tid] = atomicAdd(&bucket_cursor[tid], lcnt[tid]);
    __syncthreads();
    // exclusive scan + reset (serial over 147 — negligible)
    if (tid == 0) {
        int run = 0;
        for (int b = 0; b < NBUCK; ++b) { lscan[b] = run; run += lcnt[b]; lcnt[b] = 0; }
        lscan[NBUCK] = run;
    }
    __syncthreads();
    // place into LDS stage
    for (int i = tid; i < nE; i += 256) {
        int r = rows[e0 + i];
        int b = r >> 10;
        int lidx = atomicAdd(&lcnt[b], 1);
        int slot = lscan[b] + lidx;
        uint2 p;
        p.x = ((uint32_t)(r & 1023) << 18) | (uint32_t)cols[e0 + i];
        p.y = ftoi(vals[e0 + i]);
        stage[slot] = p;
        slotb[slot] = (u16)b;
    }
    __syncthreads();
    // copy out: contiguous per bucket-group -> coalesced spans
    for (int s = tid; s < nE; s += 256) {
        int b = slotb[s];
        etmp[gstart[b] + (s - lscan[b])] = stage[s];
    }
}

// ---------------- pass 2: exact CSR placement, per-bucket LDS cursors ----------------
__global__ __launch_bounds__(1024) void k_place(const int* __restrict__ row_ptr,
                                                const uint2* __restrict__ etmp,
                                                uint2* __restrict__ efin) {
    __shared__ int lcur[1024];
    int b = blockIdx.x;
    int base = b << 10;
    int nrows = N_NODES - base; if (nrows > 1024) nrows = 1024;
    for (int i = threadIdx.x; i < nrows; i += 1024) lcur[i] = row_ptr[base + i];
    __syncthreads();
    int bstart = row_ptr[base];
    int bend   = row_ptr[base + nrows];
    for (int i = bstart + (int)threadIdx.x; i < bend; i += 1024) {
        uint2 p = etmp[i];
        int rl = (int)(p.x >> 18);
        int pos = atomicAdd(&lcur[rl], 1);
        uint2 o; o.x = p.x & 0x3FFFFu; o.y = p.y;
        efin[pos] = o;   // within a 1-block-owned 262 KB window -> L2-combined
    }
}

// ---------------- weight transpose fp32 -> bf16 ----------------
__global__ __launch_bounds__(256) void k_transpose(const float* __restrict__ W,
                                                   u16* __restrict__ WT, int K, int N) {
    int i = blockIdx.x * 256 + threadIdx.x;
    if (i >= K * N) return;
    int k = i / N, n = i - k * N;
    WT[n * K + k] = f2bf(W[i]);
}

// ---------------- MFMA GEMM, LDS-staged B^T: C[M,N] = A@B + rs*bias ----------------
// grid (ceil(M/64), N/64), block 256 = 4 waves; wave w owns rows m0+16w..+15, all 4 n-subtiles.
__global__ __launch_bounds__(256) void k_gemm(const u16* __restrict__ A, int M, int K,
                                              const u16* __restrict__ BT,
                                              const float* __restrict__ bias,
                                              const float* __restrict__ rowscale,
                                              u16* __restrict__ C, int N, int relu) {
    __shared__ u16 lbt[64 * 264];            // 64 x (K+8), K<=256 -> 33.8 KB
    int tid = threadIdx.x;
    int lane = tid & 63, wid = tid >> 6;
    int m0 = blockIdx.x * 64;
    int n0 = blockIdx.y * 64;
    const int KP = K + 8;
    int cpr = K / 8;
    for (int idx = tid; idx < 64 * cpr; idx += 256) {
        int r = idx / cpr, c = idx - r * cpr;
        *(uint4*)(void*)(lbt + r * KP + c * 8) =
            *(const uint4*)(const void*)(BT + (size_t)(n0 + r) * K + c * 8);
    }
    __syncthreads();
    int rn = lane & 15;
    int kq = (lane >> 4) * 8;
    int mrow = m0 + wid * 16 + rn;
    int mclamp = mrow < M ? mrow : M - 1;
    const u16* aptr = A + (size_t)mclamp * K + kq;
    floatx4 acc0 = {0.f,0.f,0.f,0.f}, acc1 = acc0, acc2 = acc0, acc3 = acc0;
    for (int kt = 0; kt < K; kt += 32) {
        short8 a  = *(const short8*)(const void*)(aptr + kt);
        short8 b0 = *(const short8*)(const void*)(lbt + ( 0 + rn) * KP + kq + kt);
        short8 b1 = *(const short8*)(const void*)(lbt + (16 + rn) * KP + kq + kt);
        short8 b2 = *(const short8*)(const void*)(lbt + (32 + rn) * KP + kq + kt);
        short8 b3 = *(const short8*)(const void*)(lbt + (48 + rn) * KP + kq + kt);
        acc0 = __builtin_amdgcn_mfma_f32_16x16x32_bf16(a, b0, acc0, 0, 0, 0);
        acc1 = __builtin_amdgcn_mfma_f32_16x16x32_bf16(a, b1, acc1, 0, 0, 0);
        acc2 = __builtin_amdgcn_mfma_f32_16x16x32_bf16(a, b2, acc2, 0, 0, 0);
        acc3 = __builtin_amdgcn_mfma_f32_16x16x32_bf16(a, b3, acc3, 0, 0, 0);
    }
    int rbase = m0 + wid * 16 + (lane >> 4) * 4;   // C/D: col=lane&15, row=(lane>>4)*4+i
    floatx4 accs[4] = {acc0, acc1, acc2, acc3};
    for (int j = 0; j < 4; ++j) {
        int col = n0 + j * 16 + rn;
        float bs = bias[col];
        for (int i = 0; i < 4; ++i) {
            int row = rbase + i;
            if (row < M) {
                float rs = rowscale ? rowscale[row] : 1.0f;
                float v = accs[j][i] + rs * bs;
                if (relu) v = v < 0.f ? 0.f : v;   // NaN-propagating
                C[(size_t)row * N + col] = f2bf(v);
            }
        }
    }
}

// ---------------- aggregation (NF=128): one wave per row, 4-deep pipelined ----------------
__global__ __launch_bounds__(256) void k_agg(const u16* __restrict__ t,
                                             const int* __restrict__ row_ptr,
                                             const uint2* __restrict__ edges,
                                             u16* __restrict__ agg,
                                             float* __restrict__ rowsum) {
    int row = blockIdx.x * 4 + (threadIdx.x >> 6);
    int lane = threadIdx.x & 63;
    if (row >= N_NODES) return;
    float a0 = 0.f, a1 = 0.f, sv = 0.f;
    int s = row_ptr[row], e = row_ptr[row + 1];
    int i = s;
    for (; i + 4 <= e; i += 4) {
        uint2 e0 = edges[i], e1 = edges[i + 1], e2 = edges[i + 2], e3 = edges[i + 3];
        uint32_t r0 = *(const uint32_t*)(const void*)(t + (size_t)e0.x * 128 + lane * 2);
        uint32_t r1 = *(const uint32_t*)(const void*)(t + (size_t)e1.x * 128 + lane * 2);
        uint32_t r2 = *(const uint32_t*)(const void*)(t + (size_t)e2.x * 128 + lane * 2);
        uint32_t r3 = *(const uint32_t*)(const void*)(t + (size_t)e3.x * 128 + lane * 2);
        float v0 = itof(e0.y), v1 = itof(e1.y), v2 = itof(e2.y), v3 = itof(e3.y);
        a0 += v0 * bf2f((u16)(r0 & 0xffffu)); a1 += v0 * bf2f((u16)(r0 >> 16));
        a0 += v1 * bf2f((u16)(r1 & 0xffffu)); a1 += v1 * bf2f((u16)(r1 >> 16));
        a0 += v2 * bf2f((u16)(r2 & 0xffffu)); a1 += v2 * bf2f((u16)(r2 >> 16));
        a0 += v3 * bf2f((u16)(r3 & 0xffffu)); a1 += v3 * bf2f((u16)(r3 >> 16));
        sv += v0 + v1 + v2 + v3;
    }
    for (; i < e; ++i) {
        uint2 e0 = edges[i];
        uint32_t r0 = *(const uint32_t*)(const void*)(t + (size_t)e0.x * 128 + lane * 2);
        float v0 = itof(e0.y);
        a0 += v0 * bf2f((u16)(r0 & 0xffffu)); a1 += v0 * bf2f((u16)(r0 >> 16));
        sv += v0;
    }
    uint32_t w = (uint32_t)f2bf(a0) | ((uint32_t)f2bf(a1) << 16);
    *(uint32_t*)(void*)(agg + (size_t)row * 128 + lane * 2) = w;
    if (rowsum != nullptr && lane == 0) rowsum[row] = sv;
}

// ---------------- BatchNorm stats ----------------
__global__ __launch_bounds__(256) void k_bnstats(const u16* __restrict__ agg,
                                                 float* __restrict__ stats, int NF) {
    int tid = threadIdx.x;
    int rpb = 256 / NF;
    int f = tid & (NF - 1);
    int r0 = blockIdx.x * rpb + tid / NF;
    int rs = gridDim.x * rpb;
    float s = 0.f, s2 = 0.f;
    for (int row = r0; row < N_NODES; row += rs) {
        float v = bf2f(agg[(size_t)row * NF + f]);
        s += v; s2 += v * v;
    }
    atomicAdd(&stats[f], s);
    atomicAdd(&stats[NF + f], s2);
}

// ---------------- BatchNorm apply + ReLU -> bf16 ----------------
__global__ __launch_bounds__(256) void k_bnapply(const u16* __restrict__ agg,
                                                 const float* __restrict__ stats,
                                                 const float* __restrict__ g,
                                                 const float* __restrict__ beta,
                                                 u16* __restrict__ x, int NF) {
    size_t idx = (size_t)blockIdx.x * 256 + threadIdx.x;
    if (idx >= (size_t)N_NODES * NF) return;
    int f = (int)(idx & (size_t)(NF - 1));
    float mu = stats[f] * (1.0f / N_NODES);
    float var = stats[NF + f] * (1.0f / N_NODES) - mu * mu;
    float sc = rsqrtf(var + EPSV) * g[f];
    float v = (bf2f(agg[idx]) - mu) * sc + beta[f];
    x[idx] = f2bf(v < 0.f ? 0.f : v);
}

// ---------------- gather u||v with fused BN2+ReLU -> comb [B,256] bf16 ----------------
__global__ __launch_bounds__(256) void k_gatherBN(const int* __restrict__ ui,
                                                  const int* __restrict__ ii,
                                                  const u16* __restrict__ agg2,
                                                  const float* __restrict__ stats,
                                                  const float* __restrict__ g,
                                                  const float* __restrict__ beta,
                                                  u16* __restrict__ comb) {
    int item = blockIdx.x * 4 + (threadIdx.x >> 6);
    int lane = threadIdx.x & 63;
    if (item >= BATCH) return;
    int node = (lane < 32) ? ui[item] : (N_USERS + ii[item]);
    int fb = (lane & 31) * 4;
    uint2 r = *(const uint2*)(const void*)(agg2 + (size_t)node * H2 + fb);
    float vv[4] = { bf2f((u16)(r.x & 0xffffu)), bf2f((u16)(r.x >> 16)),
                    bf2f((u16)(r.y & 0xffffu)), bf2f((u16)(r.y >> 16)) };
    u16 o[4];
    for (int j = 0; j < 4; ++j) {
        int f = fb + j;
        float mu = stats[f] * (1.0f / N_NODES);
        float var = stats[H2 + f] * (1.0f / N_NODES) - mu * mu;
        float sc = rsqrtf(var + EPSV) * g[f];
        float v = (vv[j] - mu) * sc + beta[f];
        o[j] = f2bf(v < 0.f ? 0.f : v);
    }
    uint2 w;
    w.x = (uint32_t)o[0] | ((uint32_t)o[1] << 16);
    w.y = (uint32_t)o[2] | ((uint32_t)o[3] << 16);
    *(uint2*)(void*)(comb + (size_t)item * (2 * H2) + lane * 4) = w;
}

// ---------------- final dot ----------------
__global__ __launch_bounds__(256) void k_final(const u16* __restrict__ h,
                                               const float* __restrict__ P2,
                                               const float* __restrict__ pb2,
                                               float* __restrict__ out) {
    int item = blockIdx.x * 4 + (threadIdx.x >> 6);
    int lane = threadIdx.x & 63;
    if (item >= BATCH) return;
    float a = bf2f(h[(size_t)item * H2 + lane])      * P2[lane]
            + bf2f(h[(size_t)item * H2 + 64 + lane]) * P2[64 + lane];
    for (int off = 32; off > 0; off >>= 1) a += __shfl_down(a, off, 64);
    if (lane == 0) out[item] = a + pb2[0];
}

extern "C" void kernel_launch(void* const* d_in, const int* in_sizes, int n_in,
                              void* d_out, int out_size, void* d_ws, size_t ws_size,
                              hipStream_t stream) {
    (void)in_sizes; (void)n_in; (void)ws_size;
    const int* user_indices = (const int*)d_in[0];
    const int* item_indices = (const int*)d_in[1];
    const int* edge_rows    = (const int*)d_in[2];
    const int* edge_cols    = (const int*)d_in[3];
    const float* edge_vals = (const float*)d_in[4];
    const float* user_emb  = (const float*)d_in[5];
    const float* item_emb  = (const float*)d_in[6];
    const float* W1    = (const float*)d_in[7];
    const float* b1    = (const float*)d_in[8];
    const float* g1    = (const float*)d_in[9];
    const float* beta1 = (const float*)d_in[10];
    const float* W2    = (const float*)d_in[11];
    const float* b2    = (const float*)d_in[12];
    const float* g2    = (const float*)d_in[13];
    const float* beta2 = (const float*)d_in[14];
    const float* P1    = (const float*)d_in[15];
    const float* pb1   = (const float*)d_in[16];
    const float* P2    = (const float*)d_in[17];
    const float* pb2   = (const float*)d_in[18];
    float* out = (float*)d_out;

    // workspace layout (~195 MB)
    char* ws = (char*)d_ws;
    size_t off = 0;
    auto alloc = [&](size_t bytes) -> char* {
        char* p = ws + off;
        off = (off + bytes + 255) & ~(size_t)255;
        return p;
    };
    int*   cnt      = (int*)alloc(sizeof(int) * N_NODES);
    int*   row_ptr  = (int*)alloc(sizeof(int) * (N_NODES + 1));
    int*   bsum     = (int*)alloc(sizeof(int) * 1024);
    int*   bcursor  = (int*)alloc(sizeof(int) * 256);
    float* rowsum   = (float*)alloc(sizeof(float) * N_NODES);
    float* stats1   = (float*)alloc(sizeof(float) * 2 * H1);
    float* stats2   = (float*)alloc(sizeof(float) * 2 * H2);
    u16* WT1 = (u16*)alloc(2 * D0 * H1);
    u16* WT2 = (u16*)alloc(2 * H1 * H2);
    u16* PT1 = (u16*)alloc(2 * 2 * H2 * H2);
    uint2* efin = (uint2*)alloc(8 * (size_t)NEDGE);     // final CSR edges
    // R1 (76.8 MB): xb | aggx, later x1 (full)
    u16* R1   = (u16*)alloc(2 * (size_t)N_NODES * H1);
    u16* xb   = R1;
    u16* aggx = R1 + (size_t)N_NODES * D0;
    u16* x1   = R1;
    // R2 (76.8 MB): etmp (sort scratch) -> agg1 -> {t2 | agg2} -> {comb+hbuf | agg2}
    u16* R2   = (u16*)alloc(2 * (size_t)N_NODES * H1);
    uint2* etmp = (uint2*)R2;                            // 38.4 MB, dead after k_place
    u16* agg1 = R2;
    u16* t2   = R2;
    u16* agg2 = R2 + (size_t)N_NODES * H2;
    u16* comb = R2;
    u16* hbuf = R2 + (size_t)BATCH * 2 * H2;

    // canary (distinguish failure modes)
    k_fillf<<<(out_size + 255) / 256, 256, 0, stream>>>(out, out_size, 2.0f);

    // zero-init
    k_zero<<<(N_NODES + 255) / 256, 256, 0, stream>>>(cnt, N_NODES);
    k_zero<<<2, 256, 0, stream>>>((int*)stats1, 2 * H1);
    k_zero<<<1, 256, 0, stream>>>((int*)stats2, 2 * H2);

    // x -> bf16
    k_cvt<<<(N_NODES * D0 / 4 + 255) / 256, 256, 0, stream>>>(user_emb, item_emb, xb);

    // CSR build: hist -> scan -> bucket (pass 1) -> place (pass 2)
    k_hist<<<(NEDGE + 255) / 256, 256, 0, stream>>>(edge_rows, cnt);
    k_scan1<<<(N_NODES + 255) / 256, 256, 0, stream>>>(cnt, bsum);
    k_scan2<<<1, 256, 0, stream>>>(bsum, row_ptr);
    k_scan3<<<(N_NODES + 255) / 256, 256, 0, stream>>>(cnt, bsum, row_ptr);
    k_binit<<<1, 256, 0, stream>>>(row_ptr, bcursor);
    k_bucket<<<(NEDGE + BCHUNK - 1) / BCHUNK, 256, 0, stream>>>(
        edge_rows, edge_cols, edge_vals, bcursor, etmp);
    k_place<<<NBUCK, 1024, 0, stream>>>(row_ptr, etmp, efin);

    // weight transposes fp32 -> bf16 (B^T layout)
    k_transpose<<<(D0 * H1 + 255) / 256, 256, 0, stream>>>(W1, WT1, D0, H1);
    k_transpose<<<(H1 * H2 + 255) / 256, 256, 0, stream>>>(W2, WT2, H1, H2);
    k_transpose<<<(2 * H2 * H2 + 255) / 256, 256, 0, stream>>>(P1, PT1, 2 * H2, H2);

    // layer 1 (agg-then-GEMM via linearity): aggx = agg(xb); agg1 = aggx@W1 + s_r*b1
    k_agg<<<N_NODES / 4, 256, 0, stream>>>(xb, row_ptr, efin, aggx, rowsum);
    k_gemm<<<dim3((N_NODES + 63) / 64, H1 / 64), 256, 0, stream>>>(
        aggx, N_NODES, D0, WT1, b1, rowsum, agg1, H1, 0);
    k_bnstats<<<512, 256, 0, stream>>>(agg1, stats1, H1);
    k_bnapply<<<(N_NODES * H1) / 256, 256, 0, stream>>>(agg1, stats1, g1, beta1, x1, H1);

    // layer 2 (GEMM-then-agg): t2 = x1@W2 + b2 ; agg2 = agg(t2)
    k_gemm<<<dim3((N_NODES + 63) / 64, H2 / 64), 256, 0, stream>>>(
        x1, N_NODES, H1, WT2, b2, nullptr, t2, H2, 0);
    k_agg<<<N_NODES / 4, 256, 0, stream>>>(t2, row_ptr, efin, agg2, nullptr);
    k_bnstats<<<512, 256, 0, stream>>>(agg2, stats2, H2);

    // head: gather with fused BN2+ReLU, MLP, dot
    k_gatherBN<<<BATCH / 4, 256, 0, stream>>>(user_indices, item_indices, agg2,
                                              stats2, g2, beta2, comb);
    k_gemm<<<dim3(BATCH / 64, H2 / 64), 256, 0, stream>>>(
        comb, BATCH, 2 * H2, PT1, pb1, nullptr, hbuf, H2, 1);
    k_final<<<BATCH / 4, 256, 0, stream>>>(hbuf, P2, pb2, out);
}

// Round 6
// 1033.097 us; speedup vs baseline: 2.3874x; 1.1578x over previous
//
#include <hip/hip_runtime.h>
#include <stdint.h>

#define N_USERS 100000
#define N_NODES 150000
#define D0      128
#define H1      256
#define H2      128
#define NEDGE   4800000
#define BATCH   16384
#define EPSV    1e-5f
#define NBUCK   147          // ceil(150000/1024) coarse buckets (1024 rows each)
#define BCHUNK  4096         // edges per k_bucket block
#define CCHUNK  16384        // edges per k_bcount block

typedef short short8  __attribute__((ext_vector_type(8)));   // 8 bf16 MFMA frag
typedef float floatx4 __attribute__((ext_vector_type(4)));
typedef unsigned short u16;

__device__ inline float bf2f(u16 u) {
    union { float f; uint32_t i; } x; x.i = ((uint32_t)u) << 16; return x.f;
}
__device__ inline u16 f2bf(float f) {
    union { float f; uint32_t i; } x; x.f = f;
    return (u16)((x.i + 0x7FFFu + ((x.i >> 16) & 1u)) >> 16);  // RNE
}
__device__ inline float itof(uint32_t u) {
    union { float f; uint32_t i; } x; x.i = u; return x.f;
}
__device__ inline uint32_t ftoi(float f) {
    union { float f; uint32_t i; } x; x.f = f; return x.i;
}

// ---------------- utility ----------------
__global__ __launch_bounds__(256) void k_zero(int* __restrict__ p, int n) {
    int i = blockIdx.x * 256 + threadIdx.x;
    if (i < n) p[i] = 0;
}
__global__ __launch_bounds__(256) void k_fillf(float* __restrict__ p, int n, float v) {
    int i = blockIdx.x * 256 + threadIdx.x;
    if (i < n) p[i] = v;
}

// ---------------- x (fp32 user||item) -> bf16 xb ----------------
__global__ __launch_bounds__(256) void k_cvt(const float* __restrict__ ue,
                                             const float* __restrict__ ie,
                                             u16* __restrict__ xb) {
    int i = (blockIdx.x * 256 + threadIdx.x) * 4;
    const int NU = N_USERS * D0;
    const int NT = N_NODES * D0;
    if (i >= NT) return;
    const float* src = (i < NU) ? (ue + i) : (ie + (i - NU));
    float4 f = *(const float4*)(const void*)src;
    uint2 w;
    w.x = (uint32_t)f2bf(f.x) | ((uint32_t)f2bf(f.y) << 16);
    w.y = (uint32_t)f2bf(f.z) | ((uint32_t)f2bf(f.w) << 16);
    *(uint2*)(void*)(xb + i) = w;
}

// ---------------- bucket counting: LDS histogram of 147 buckets ----------------
__global__ __launch_bounds__(256) void k_bcount(const int* __restrict__ rows,
                                                int* __restrict__ bcount) {
    __shared__ int h[NBUCK];
    int tid = threadIdx.x;
    for (int i = tid; i < NBUCK; i += 256) h[i] = 0;
    __syncthreads();
    int e0 = blockIdx.x * CCHUNK;
    int nE = NEDGE - e0; if (nE > CCHUNK) nE = CCHUNK;
    for (int i = tid; i < nE; i += 256) atomicAdd(&h[rows[e0 + i] >> 10], 1);
    __syncthreads();
    for (int i = tid; i < NBUCK; i += 256)
        if (h[i] > 0) atomicAdd(&bcount[i], h[i]);
}

// single-block scan of bucket counts -> bucket_base / bucket_cursor; row_ptr[N]=NEDGE
__global__ __launch_bounds__(256) void k_bscan(const int* __restrict__ bcount,
                                               int* __restrict__ bucket_base,
                                               int* __restrict__ bucket_cursor,
                                               int* __restrict__ row_ptr) {
    int tid = threadIdx.x;
    int c = (tid < NBUCK) ? bcount[tid] : 0;
    int lane = tid & 63, wid = tid >> 6;
    int v = c;
    for (int off = 1; off < 64; off <<= 1) {
        int u = __shfl_up(v, off, 64);
        if (lane >= off) v += u;
    }
    __shared__ int wsum[4];
    if (lane == 63) wsum[wid] = v;
    __syncthreads();
    if (tid == 0) {
        int acc = 0;
        for (int w = 0; w < 4; ++w) { int t = wsum[w]; wsum[w] = acc; acc += t; }
    }
    __syncthreads();
    int ex = wsum[wid] + (v - c);
    if (tid < NBUCK) { bucket_base[tid] = ex; bucket_cursor[tid] = ex; }
    if (tid == 0) { bucket_base[NBUCK] = NEDGE; row_ptr[N_NODES] = NEDGE; }
}

// ---------------- pass 1: LDS-staged bucket append (coalesced spans) ----------------
// payload packed: x = (rowlocal<<18) | col, y = val bits
__global__ __launch_bounds__(256) void k_bucket(const int* __restrict__ rows,
                                                const int* __restrict__ cols,
                                                const float* __restrict__ vals,
                                                int* __restrict__ bucket_cursor,
                                                uint2* __restrict__ etmp) {
    __shared__ uint2 stage[BCHUNK];        // 32 KB
    __shared__ u16   slotb[BCHUNK];        // 8 KB
    __shared__ int   lcnt[NBUCK + 1];
    __shared__ int   lscan[NBUCK + 1];
    __shared__ int   gstart[NBUCK];
    int tid = threadIdx.x;
    int e0 = blockIdx.x * BCHUNK;
    int nE = NEDGE - e0; if (nE > BCHUNK) nE = BCHUNK;

    for (int i = tid; i <= NBUCK; i += 256) lcnt[i] = 0;
    __syncthreads();
    for (int i = tid; i < nE; i += 256) atomicAdd(&lcnt[rows[e0 + i] >> 10], 1);
    __syncthreads();
    if (tid < NBUCK) gstart[tid] = atomicAdd(&bucket_cursor[tid], lcnt[tid]);
    __syncthreads();
    if (tid == 0) {
        int run = 0;
        for (int b = 0; b < NBUCK; ++b) { lscan[b] = run; run += lcnt[b]; lcnt[b] = 0; }
        lscan[NBUCK] = run;
    }
    __syncthreads();
    for (int i = tid; i < nE; i += 256) {
        int r = rows[e0 + i];
        int b = r >> 10;
        int lidx = atomicAdd(&lcnt[b], 1);
        int slot = lscan[b] + lidx;
        uint2 p;
        p.x = ((uint32_t)(r & 1023) << 18) | (uint32_t)cols[e0 + i];
        p.y = ftoi(vals[e0 + i]);
        stage[slot] = p;
        slotb[slot] = (u16)b;
    }
    __syncthreads();
    for (int s = tid; s < nE; s += 256) {
        int b = slotb[s];
        etmp[gstart[b] + (s - lscan[b])] = stage[s];
    }
}

// ---------------- pass 2: per-bucket row count + LDS scan -> row_ptr; exact placement ----------------
__global__ __launch_bounds__(1024) void k_place2(const int* __restrict__ bucket_base,
                                                 const uint2* __restrict__ etmp,
                                                 int* __restrict__ row_ptr,
                                                 uint2* __restrict__ efin) {
    __shared__ int lcnt[1024];
    __shared__ int lcur[1024];
    __shared__ int wsum[16];
    int b = blockIdx.x;
    int tid = threadIdx.x;
    int base = b << 10;
    int bstart = bucket_base[b];
    int bend   = bucket_base[b + 1];
    lcnt[tid] = 0;
    __syncthreads();
    // pass 2a: count rows within bucket
    for (int i = bstart + tid; i < bend; i += 1024)
        atomicAdd(&lcnt[etmp[i].x >> 18], 1);
    __syncthreads();
    // exclusive scan over 1024 counts
    int c = lcnt[tid];
    int lane = tid & 63, wid = tid >> 6;
    int v = c;
    for (int off = 1; off < 64; off <<= 1) {
        int u = __shfl_up(v, off, 64);
        if (lane >= off) v += u;
    }
    if (lane == 63) wsum[wid] = v;
    __syncthreads();
    if (tid == 0) {
        int acc = 0;
        for (int w = 0; w < 16; ++w) { int t = wsum[w]; wsum[w] = acc; acc += t; }
    }
    __syncthreads();
    int ex = wsum[wid] + (v - c);
    int gpos = bstart + ex;
    if (base + tid < N_NODES) row_ptr[base + tid] = gpos;
    lcur[tid] = gpos;
    __syncthreads();
    // pass 2b: place
    for (int i = bstart + tid; i < bend; i += 1024) {
        uint2 p = etmp[i];
        int rl = (int)(p.x >> 18);
        int pos = atomicAdd(&lcur[rl], 1);
        uint2 o; o.x = p.x & 0x3FFFFu; o.y = p.y;
        efin[pos] = o;   // within a 1-block-owned 262 KB window -> L2-combined
    }
}

// ---------------- weight transpose fp32 -> bf16 ----------------
__global__ __launch_bounds__(256) void k_transpose(const float* __restrict__ W,
                                                   u16* __restrict__ WT, int K, int N) {
    int i = blockIdx.x * 256 + threadIdx.x;
    if (i >= K * N) return;
    int k = i / N, n = i - k * N;
    WT[n * K + k] = f2bf(W[i]);
}

// ---------------- MFMA GEMM, LDS-staged B^T: C[M,N] = A@B + rs*bias ----------------
__global__ __launch_bounds__(256) void k_gemm(const u16* __restrict__ A, int M, int K,
                                              const u16* __restrict__ BT,
                                              const float* __restrict__ bias,
                                              const float* __restrict__ rowscale,
                                              u16* __restrict__ C, int N, int relu) {
    __shared__ u16 lbt[64 * 264];            // 64 x (K+8), K<=256 -> 33.8 KB
    int tid = threadIdx.x;
    int lane = tid & 63, wid = tid >> 6;
    int m0 = blockIdx.x * 64;
    int n0 = blockIdx.y * 64;
    const int KP = K + 8;
    int cpr = K / 8;
    for (int idx = tid; idx < 64 * cpr; idx += 256) {
        int r = idx / cpr, c = idx - r * cpr;
        *(uint4*)(void*)(lbt + r * KP + c * 8) =
            *(const uint4*)(const void*)(BT + (size_t)(n0 + r) * K + c * 8);
    }
    __syncthreads();
    int rn = lane & 15;
    int kq = (lane >> 4) * 8;
    int mrow = m0 + wid * 16 + rn;
    int mclamp = mrow < M ? mrow : M - 1;
    const u16* aptr = A + (size_t)mclamp * K + kq;
    floatx4 acc0 = {0.f,0.f,0.f,0.f}, acc1 = acc0, acc2 = acc0, acc3 = acc0;
    for (int kt = 0; kt < K; kt += 32) {
        short8 a  = *(const short8*)(const void*)(aptr + kt);
        short8 b0 = *(const short8*)(const void*)(lbt + ( 0 + rn) * KP + kq + kt);
        short8 b1 = *(const short8*)(const void*)(lbt + (16 + rn) * KP + kq + kt);
        short8 b2 = *(const short8*)(const void*)(lbt + (32 + rn) * KP + kq + kt);
        short8 b3 = *(const short8*)(const void*)(lbt + (48 + rn) * KP + kq + kt);
        acc0 = __builtin_amdgcn_mfma_f32_16x16x32_bf16(a, b0, acc0, 0, 0, 0);
        acc1 = __builtin_amdgcn_mfma_f32_16x16x32_bf16(a, b1, acc1, 0, 0, 0);
        acc2 = __builtin_amdgcn_mfma_f32_16x16x32_bf16(a, b2, acc2, 0, 0, 0);
        acc3 = __builtin_amdgcn_mfma_f32_16x16x32_bf16(a, b3, acc3, 0, 0, 0);
    }
    int rbase = m0 + wid * 16 + (lane >> 4) * 4;   // C/D: col=lane&15, row=(lane>>4)*4+i
    floatx4 accs[4] = {acc0, acc1, acc2, acc3};
    for (int j = 0; j < 4; ++j) {
        int col = n0 + j * 16 + rn;
        float bs = bias[col];
        for (int i = 0; i < 4; ++i) {
            int row = rbase + i;
            if (row < M) {
                float rs = rowscale ? rowscale[row] : 1.0f;
                float v = accs[j][i] + rs * bs;
                if (relu) v = v < 0.f ? 0.f : v;   // NaN-propagating
                C[(size_t)row * N + col] = f2bf(v);
            }
        }
    }
}

// ---------------- aggregation (NF=128): one wave per row, 8-deep pipelined ----------------
__global__ __launch_bounds__(256) void k_agg(const u16* __restrict__ t,
                                             const int* __restrict__ row_ptr,
                                             const uint2* __restrict__ edges,
                                             u16* __restrict__ agg,
                                             float* __restrict__ rowsum) {
    int row = blockIdx.x * 4 + (threadIdx.x >> 6);
    int lane = threadIdx.x & 63;
    if (row >= N_NODES) return;
    float a0 = 0.f, a1 = 0.f, sv = 0.f;
    int s = row_ptr[row], e = row_ptr[row + 1];
    int i = s;
    for (; i + 8 <= e; i += 8) {
        uint2 ee[8];
        uint32_t rr[8];
        #pragma unroll
        for (int j = 0; j < 8; ++j) ee[j] = edges[i + j];
        #pragma unroll
        for (int j = 0; j < 8; ++j)
            rr[j] = *(const uint32_t*)(const void*)(t + (size_t)ee[j].x * 128 + lane * 2);
        #pragma unroll
        for (int j = 0; j < 8; ++j) {
            float v = itof(ee[j].y);
            a0 += v * bf2f((u16)(rr[j] & 0xffffu));
            a1 += v * bf2f((u16)(rr[j] >> 16));
            sv += v;
        }
    }
    for (; i < e; ++i) {
        uint2 e0 = edges[i];
        uint32_t r0 = *(const uint32_t*)(const void*)(t + (size_t)e0.x * 128 + lane * 2);
        float v0 = itof(e0.y);
        a0 += v0 * bf2f((u16)(r0 & 0xffffu)); a1 += v0 * bf2f((u16)(r0 >> 16));
        sv += v0;
    }
    uint32_t w = (uint32_t)f2bf(a0) | ((uint32_t)f2bf(a1) << 16);
    *(uint32_t*)(void*)(agg + (size_t)row * 128 + lane * 2) = w;
    if (rowsum != nullptr && lane == 0) rowsum[row] = sv;
}

// ---------------- BatchNorm stats ----------------
__global__ __launch_bounds__(256) void k_bnstats(const u16* __restrict__ agg,
                                                 float* __restrict__ stats, int NF) {
    int tid = threadIdx.x;
    int rpb = 256 / NF;
    int f = tid & (NF - 1);
    int r0 = blockIdx.x * rpb + tid / NF;
    int rs = gridDim.x * rpb;
    float s = 0.f, s2 = 0.f;
    for (int row = r0; row < N_NODES; row += rs) {
        float v = bf2f(agg[(size_t)row * NF + f]);
        s += v; s2 += v * v;
    }
    atomicAdd(&stats[f], s);
    atomicAdd(&stats[NF + f], s2);
}

// ---------------- BatchNorm apply + ReLU -> bf16 ----------------
__global__ __launch_bounds__(256) void k_bnapply(const u16* __restrict__ agg,
                                                 const float* __restrict__ stats,
                                                 const float* __restrict__ g,
                                                 const float* __restrict__ beta,
                                                 u16* __restrict__ x, int NF) {
    size_t idx = (size_t)blockIdx.x * 256 + threadIdx.x;
    if (idx >= (size_t)N_NODES * NF) return;
    int f = (int)(idx & (size_t)(NF - 1));
    float mu = stats[f] * (1.0f / N_NODES);
    float var = stats[NF + f] * (1.0f / N_NODES) - mu * mu;
    float sc = rsqrtf(var + EPSV) * g[f];
    float v = (bf2f(agg[idx]) - mu) * sc + beta[f];
    x[idx] = f2bf(v < 0.f ? 0.f : v);
}

// ---------------- gather u||v with fused BN2+ReLU -> comb [B,256] bf16 ----------------
__global__ __launch_bounds__(256) void k_gatherBN(const int* __restrict__ ui,
                                                  const int* __restrict__ ii,
                                                  const u16* __restrict__ agg2,
                                                  const float* __restrict__ stats,
                                                  const float* __restrict__ g,
                                                  const float* __restrict__ beta,
                                                  u16* __restrict__ comb) {
    int item = blockIdx.x * 4 + (threadIdx.x >> 6);
    int lane = threadIdx.x & 63;
    if (item >= BATCH) return;
    int node = (lane < 32) ? ui[item] : (N_USERS + ii[item]);
    int fb = (lane & 31) * 4;
    uint2 r = *(const uint2*)(const void*)(agg2 + (size_t)node * H2 + fb);
    float vv[4] = { bf2f((u16)(r.x & 0xffffu)), bf2f((u16)(r.x >> 16)),
                    bf2f((u16)(r.y & 0xffffu)), bf2f((u16)(r.y >> 16)) };
    u16 o[4];
    for (int j = 0; j < 4; ++j) {
        int f = fb + j;
        float mu = stats[f] * (1.0f / N_NODES);
        float var = stats[H2 + f] * (1.0f / N_NODES) - mu * mu;
        float sc = rsqrtf(var + EPSV) * g[f];
        float v = (vv[j] - mu) * sc + beta[f];
        o[j] = f2bf(v < 0.f ? 0.f : v);
    }
    uint2 w;
    w.x = (uint32_t)o[0] | ((uint32_t)o[1] << 16);
    w.y = (uint32_t)o[2] | ((uint32_t)o[3] << 16);
    *(uint2*)(void*)(comb + (size_t)item * (2 * H2) + lane * 4) = w;
}

// ---------------- final dot ----------------
__global__ __launch_bounds__(256) void k_final(const u16* __restrict__ h,
                                               const float* __restrict__ P2,
                                               const float* __restrict__ pb2,
                                               float* __restrict__ out) {
    int item = blockIdx.x * 4 + (threadIdx.x >> 6);
    int lane = threadIdx.x & 63;
    if (item >= BATCH) return;
    float a = bf2f(h[(size_t)item * H2 + lane])      * P2[lane]
            + bf2f(h[(size_t)item * H2 + 64 + lane]) * P2[64 + lane];
    for (int off = 32; off > 0; off >>= 1) a += __shfl_down(a, off, 64);
    if (lane == 0) out[item] = a + pb2[0];
}

extern "C" void kernel_launch(void* const* d_in, const int* in_sizes, int n_in,
                              void* d_out, int out_size, void* d_ws, size_t ws_size,
                              hipStream_t stream) {
    (void)in_sizes; (void)n_in; (void)ws_size;
    const int* user_indices = (const int*)d_in[0];
    const int* item_indices = (const int*)d_in[1];
    const int* edge_rows    = (const int*)d_in[2];
    const int* edge_cols    = (const int*)d_in[3];
    const float* edge_vals = (const float*)d_in[4];
    const float* user_emb  = (const float*)d_in[5];
    const float* item_emb  = (const float*)d_in[6];
    const float* W1    = (const float*)d_in[7];
    const float* b1    = (const float*)d_in[8];
    const float* g1    = (const float*)d_in[9];
    const float* beta1 = (const float*)d_in[10];
    const float* W2    = (const float*)d_in[11];
    const float* b2    = (const float*)d_in[12];
    const float* g2    = (const float*)d_in[13];
    const float* beta2 = (const float*)d_in[14];
    const float* P1    = (const float*)d_in[15];
    const float* pb1   = (const float*)d_in[16];
    const float* P2    = (const float*)d_in[17];
    const float* pb2   = (const float*)d_in[18];
    float* out = (float*)d_out;

    // workspace layout (~195 MB)
    char* ws = (char*)d_ws;
    size_t off = 0;
    auto alloc = [&](size_t bytes) -> char* {
        char* p = ws + off;
        off = (off + bytes + 255) & ~(size_t)255;
        return p;
    };
    int*   row_ptr  = (int*)alloc(sizeof(int) * (N_NODES + 1));
    int*   bcount   = (int*)alloc(sizeof(int) * (NBUCK + 1));
    int*   bbase    = (int*)alloc(sizeof(int) * (NBUCK + 1));
    int*   bcursor  = (int*)alloc(sizeof(int) * (NBUCK + 1));
    float* rowsum   = (float*)alloc(sizeof(float) * N_NODES);
    float* stats1   = (float*)alloc(sizeof(float) * 2 * H1);
    float* stats2   = (float*)alloc(sizeof(float) * 2 * H2);
    u16* WT1 = (u16*)alloc(2 * D0 * H1);
    u16* WT2 = (u16*)alloc(2 * H1 * H2);
    u16* PT1 = (u16*)alloc(2 * 2 * H2 * H2);
    uint2* efin = (uint2*)alloc(8 * (size_t)NEDGE);     // final CSR edges
    // R1 (76.8 MB): xb | aggx, later x1 (full)
    u16* R1   = (u16*)alloc(2 * (size_t)N_NODES * H1);
    u16* xb   = R1;
    u16* aggx = R1 + (size_t)N_NODES * D0;
    u16* x1   = R1;
    // R2 (76.8 MB): etmp (sort scratch) -> agg1 -> {t2 | agg2} -> {comb+hbuf | agg2}
    u16* R2   = (u16*)alloc(2 * (size_t)N_NODES * H1);
    uint2* etmp = (uint2*)R2;                            // 38.4 MB, dead after k_place2
    u16* agg1 = R2;
    u16* t2   = R2;
    u16* agg2 = R2 + (size_t)N_NODES * H2;
    u16* comb = R2;
    u16* hbuf = R2 + (size_t)BATCH * 2 * H2;

    // canary (distinguish failure modes)
    k_fillf<<<(out_size + 255) / 256, 256, 0, stream>>>(out, out_size, 2.0f);

    // zero-init
    k_zero<<<1, 256, 0, stream>>>(bcount, NBUCK + 1);
    k_zero<<<2, 256, 0, stream>>>((int*)stats1, 2 * H1);
    k_zero<<<1, 256, 0, stream>>>((int*)stats2, 2 * H2);

    // x -> bf16
    k_cvt<<<(N_NODES * D0 / 4 + 255) / 256, 256, 0, stream>>>(user_emb, item_emb, xb);

    // CSR build: bucket-count -> scan(147) -> bucket stage -> place (+row_ptr)
    k_bcount<<<(NEDGE + CCHUNK - 1) / CCHUNK, 256, 0, stream>>>(edge_rows, bcount);
    k_bscan<<<1, 256, 0, stream>>>(bcount, bbase, bcursor, row_ptr);
    k_bucket<<<(NEDGE + BCHUNK - 1) / BCHUNK, 256, 0, stream>>>(
        edge_rows, edge_cols, edge_vals, bcursor, etmp);
    k_place2<<<NBUCK, 1024, 0, stream>>>(bbase, etmp, row_ptr, efin);

    // weight transposes fp32 -> bf16 (B^T layout)
    k_transpose<<<(D0 * H1 + 255) / 256, 256, 0, stream>>>(W1, WT1, D0, H1);
    k_transpose<<<(H1 * H2 + 255) / 256, 256, 0, stream>>>(W2, WT2, H1, H2);
    k_transpose<<<(2 * H2 * H2 + 255) / 256, 256, 0, stream>>>(P1, PT1, 2 * H2, H2);

    // layer 1 (agg-then-GEMM via linearity): aggx = agg(xb); agg1 = aggx@W1 + s_r*b1
    k_agg<<<N_NODES / 4, 256, 0, stream>>>(xb, row_ptr, efin, aggx, rowsum);
    k_gemm<<<dim3((N_NODES + 63) / 64, H1 / 64), 256, 0, stream>>>(
        aggx, N_NODES, D0, WT1, b1, rowsum, agg1, H1, 0);
    k_bnstats<<<512, 256, 0, stream>>>(agg1, stats1, H1);
    k_bnapply<<<(N_NODES * H1) / 256, 256, 0, stream>>>(agg1, stats1, g1, beta1, x1, H1);

    // layer 2 (GEMM-then-agg): t2 = x1@W2 + b2 ; agg2 = agg(t2)
    k_gemm<<<dim3((N_NODES + 63) / 64, H2 / 64), 256, 0, stream>>>(
        x1, N_NODES, H1, WT2, b2, nullptr, t2, H2, 0);
    k_agg<<<N_NODES / 4, 256, 0, stream>>>(t2, row_ptr, efin, agg2, nullptr);
    k_bnstats<<<512, 256, 0, stream>>>(agg2, stats2, H2);

    // head: gather with fused BN2+ReLU, MLP, dot
    k_gatherBN<<<BATCH / 4, 256, 0, stream>>>(user_indices, item_indices, agg2,
                                              stats2, g2, beta2, comb);
    k_gemm<<<dim3(BATCH / 64, H2 / 64), 256, 0, stream>>>(
        comb, BATCH, 2 * H2, PT1, pb1, nullptr, hbuf, H2, 1);
    k_final<<<BATCH / 4, 256, 0, stream>>>(hbuf, P2, pb2, out);
}

// Round 7
// 1017.940 us; speedup vs baseline: 2.4229x; 1.0149x over previous
//
#include <hip/hip_runtime.h>
#include <stdint.h>

#define N_USERS 100000
#define N_NODES 150000
#define D0      128
#define H1      256
#define H2      128
#define NEDGE   4800000
#define BATCH   16384
#define EPSV    1e-5f
#define NBUCK   147          // ceil(150000/1024) coarse buckets (1024 rows each)
#define BCHUNK  4096         // edges per k_bucket block
#define CCHUNK  16384        // edges per k_bcount block

typedef short short8  __attribute__((ext_vector_type(8)));   // 8 bf16 MFMA frag
typedef float floatx4 __attribute__((ext_vector_type(4)));
typedef unsigned short u16;

__device__ inline float bf2f(u16 u) {
    union { float f; uint32_t i; } x; x.i = ((uint32_t)u) << 16; return x.f;
}
__device__ inline u16 f2bf(float f) {
    union { float f; uint32_t i; } x; x.f = f;
    return (u16)((x.i + 0x7FFFu + ((x.i >> 16) & 1u)) >> 16);  // RNE
}
__device__ inline float itof(uint32_t u) {
    union { float f; uint32_t i; } x; x.i = u; return x.f;
}
__device__ inline uint32_t ftoi(float f) {
    union { float f; uint32_t i; } x; x.f = f; return x.i;
}
__device__ inline uint32_t pack2(float a, float b) {
    return (uint32_t)f2bf(a) | ((uint32_t)f2bf(b) << 16);
}

// ---------------- fused init: canary + zeros ----------------
__global__ __launch_bounds__(256) void k_init(float* __restrict__ out, int out_n,
                                              int* __restrict__ bcount,
                                              float* __restrict__ stats1,
                                              float* __restrict__ stats2) {
    int i = blockIdx.x * 256 + threadIdx.x;
    if (i < out_n) out[i] = 2.0f;               // canary
    if (i < NBUCK + 1) bcount[i] = 0;
    if (i < 2 * H1) stats1[i] = 0.f;
    if (i < 2 * H2) stats2[i] = 0.f;
}

// ---------------- x (fp32 user||item) -> bf16 xb ----------------
__global__ __launch_bounds__(256) void k_cvt(const float* __restrict__ ue,
                                             const float* __restrict__ ie,
                                             u16* __restrict__ xb) {
    int i = (blockIdx.x * 256 + threadIdx.x) * 4;
    const int NU = N_USERS * D0;
    const int NT = N_NODES * D0;
    if (i >= NT) return;
    const float* src = (i < NU) ? (ue + i) : (ie + (i - NU));
    float4 f = *(const float4*)(const void*)src;
    uint2 w;
    w.x = pack2(f.x, f.y);
    w.y = pack2(f.z, f.w);
    *(uint2*)(void*)(xb + i) = w;
}

// ---------------- bucket counting: LDS histogram of 147 buckets ----------------
__global__ __launch_bounds__(256) void k_bcount(const int* __restrict__ rows,
                                                int* __restrict__ bcount) {
    __shared__ int h[NBUCK];
    int tid = threadIdx.x;
    for (int i = tid; i < NBUCK; i += 256) h[i] = 0;
    __syncthreads();
    int e0 = blockIdx.x * CCHUNK;
    int nE = NEDGE - e0; if (nE > CCHUNK) nE = CCHUNK;
    for (int i = tid; i < nE; i += 256) atomicAdd(&h[rows[e0 + i] >> 10], 1);
    __syncthreads();
    for (int i = tid; i < NBUCK; i += 256)
        if (h[i] > 0) atomicAdd(&bcount[i], h[i]);
}

// single-block scan of bucket counts -> bucket_base / bucket_cursor; row_ptr[N]=NEDGE
__global__ __launch_bounds__(256) void k_bscan(const int* __restrict__ bcount,
                                               int* __restrict__ bucket_base,
                                               int* __restrict__ bucket_cursor,
                                               int* __restrict__ row_ptr) {
    int tid = threadIdx.x;
    int c = (tid < NBUCK) ? bcount[tid] : 0;
    int lane = tid & 63, wid = tid >> 6;
    int v = c;
    for (int off = 1; off < 64; off <<= 1) {
        int u = __shfl_up(v, off, 64);
        if (lane >= off) v += u;
    }
    __shared__ int wsum[4];
    if (lane == 63) wsum[wid] = v;
    __syncthreads();
    if (tid == 0) {
        int acc = 0;
        for (int w = 0; w < 4; ++w) { int t = wsum[w]; wsum[w] = acc; acc += t; }
    }
    __syncthreads();
    int ex = wsum[wid] + (v - c);
    if (tid < NBUCK) { bucket_base[tid] = ex; bucket_cursor[tid] = ex; }
    if (tid == 0) { bucket_base[NBUCK] = NEDGE; row_ptr[N_NODES] = NEDGE; }
}

// ---------------- pass 1: LDS-staged bucket append (coalesced spans) ----------------
// payload packed: x = (rowlocal<<18) | col, y = val bits
__global__ __launch_bounds__(256) void k_bucket(const int* __restrict__ rows,
                                                const int* __restrict__ cols,
                                                const float* __restrict__ vals,
                                                int* __restrict__ bucket_cursor,
                                                uint2* __restrict__ etmp) {
    __shared__ uint2 stage[BCHUNK];        // 32 KB
    __shared__ u16   slotb[BCHUNK];        // 8 KB
    __shared__ int   lcnt[NBUCK + 1];
    __shared__ int   lscan[NBUCK + 1];
    __shared__ int   gstart[NBUCK];
    __shared__ int   wsum[4];
    int tid = threadIdx.x;
    int e0 = blockIdx.x * BCHUNK;
    int nE = NEDGE - e0; if (nE > BCHUNK) nE = BCHUNK;

    for (int i = tid; i <= NBUCK; i += 256) lcnt[i] = 0;
    __syncthreads();
    for (int i = tid; i < nE; i += 256) atomicAdd(&lcnt[rows[e0 + i] >> 10], 1);
    __syncthreads();
    int c = (tid < NBUCK) ? lcnt[tid] : 0;
    if (tid < NBUCK) gstart[tid] = atomicAdd(&bucket_cursor[tid], c);
    // wave-parallel exclusive scan of lcnt -> lscan
    {
        int lane = tid & 63, wid = tid >> 6;
        int v = c;
        for (int off = 1; off < 64; off <<= 1) {
            int u = __shfl_up(v, off, 64);
            if (lane >= off) v += u;
        }
        if (lane == 63) wsum[wid] = v;
        __syncthreads();
        if (tid == 0) {
            int acc = 0;
            for (int w = 0; w < 4; ++w) { int t = wsum[w]; wsum[w] = acc; acc += t; }
        }
        __syncthreads();
        if (tid < NBUCK) lscan[tid] = wsum[wid] + (v - c);
        for (int i = tid; i < NBUCK; i += 256) lcnt[i] = 0;
    }
    __syncthreads();
    for (int i = tid; i < nE; i += 256) {
        int r = rows[e0 + i];
        int b = r >> 10;
        int lidx = atomicAdd(&lcnt[b], 1);
        int slot = lscan[b] + lidx;
        uint2 p;
        p.x = ((uint32_t)(r & 1023) << 18) | (uint32_t)cols[e0 + i];
        p.y = ftoi(vals[e0 + i]);
        stage[slot] = p;
        slotb[slot] = (u16)b;
    }
    __syncthreads();
    for (int s = tid; s < nE; s += 256) {
        int b = slotb[s];
        etmp[gstart[b] + (s - lscan[b])] = stage[s];
    }
}

// ---------------- pass 2: per-bucket row count + LDS scan -> row_ptr; exact placement ----------------
__global__ __launch_bounds__(1024) void k_place2(const int* __restrict__ bucket_base,
                                                 const uint2* __restrict__ etmp,
                                                 int* __restrict__ row_ptr,
                                                 uint2* __restrict__ efin) {
    __shared__ int lcnt[1024];
    __shared__ int lcur[1024];
    __shared__ int wsum[16];
    int b = blockIdx.x;
    int tid = threadIdx.x;
    int base = b << 10;
    int bstart = bucket_base[b];
    int bend   = bucket_base[b + 1];
    lcnt[tid] = 0;
    __syncthreads();
    for (int i = bstart + tid; i < bend; i += 1024)
        atomicAdd(&lcnt[etmp[i].x >> 18], 1);
    __syncthreads();
    int c = lcnt[tid];
    int lane = tid & 63, wid = tid >> 6;
    int v = c;
    for (int off = 1; off < 64; off <<= 1) {
        int u = __shfl_up(v, off, 64);
        if (lane >= off) v += u;
    }
    if (lane == 63) wsum[wid] = v;
    __syncthreads();
    if (tid == 0) {
        int acc = 0;
        for (int w = 0; w < 16; ++w) { int t = wsum[w]; wsum[w] = acc; acc += t; }
    }
    __syncthreads();
    int ex = wsum[wid] + (v - c);
    int gpos = bstart + ex;
    if (base + tid < N_NODES) row_ptr[base + tid] = gpos;
    lcur[tid] = gpos;
    __syncthreads();
    for (int i = bstart + tid; i < bend; i += 1024) {
        uint2 p = etmp[i];
        int rl = (int)(p.x >> 18);
        int pos = atomicAdd(&lcur[rl], 1);
        uint2 o; o.x = p.x & 0x3FFFFu; o.y = p.y;
        efin[pos] = o;   // within a 1-block-owned 262 KB window -> L2-combined
    }
}

// ---------------- fused weight transposes fp32 -> bf16 (all segments are 32768) ----------------
__global__ __launch_bounds__(256) void k_transpose3(const float* __restrict__ W1,
                                                    const float* __restrict__ W2,
                                                    const float* __restrict__ P1,
                                                    u16* __restrict__ WT1,
                                                    u16* __restrict__ WT2,
                                                    u16* __restrict__ PT1) {
    int gi = blockIdx.x * 256 + threadIdx.x;
    int seg = gi >> 15;           // /32768
    int i = gi & 32767;
    const float* W; u16* WT; int K, N;
    if (seg == 0)      { W = W1; WT = WT1; K = D0;     N = H1; }
    else if (seg == 1) { W = W2; WT = WT2; K = H1;     N = H2; }
    else               { W = P1; WT = PT1; K = 2 * H2; N = H2; }
    int k = i / N, n = i - k * N;
    WT[n * K + k] = f2bf(W[i]);
}

// ---------------- MFMA GEMM, LDS-staged B^T: C[M,N] = A@B + rs*bias ----------------
__global__ __launch_bounds__(256) void k_gemm(const u16* __restrict__ A, int M, int K,
                                              const u16* __restrict__ BT,
                                              const float* __restrict__ bias,
                                              const float* __restrict__ rowscale,
                                              u16* __restrict__ C, int N, int relu) {
    __shared__ u16 lbt[64 * 264];            // 64 x (K+8), K<=256 -> 33.8 KB
    int tid = threadIdx.x;
    int lane = tid & 63, wid = tid >> 6;
    int m0 = blockIdx.x * 64;
    int n0 = blockIdx.y * 64;
    const int KP = K + 8;
    int cpr = K / 8;
    for (int idx = tid; idx < 64 * cpr; idx += 256) {
        int r = idx / cpr, c = idx - r * cpr;
        *(uint4*)(void*)(lbt + r * KP + c * 8) =
            *(const uint4*)(const void*)(BT + (size_t)(n0 + r) * K + c * 8);
    }
    __syncthreads();
    int rn = lane & 15;
    int kq = (lane >> 4) * 8;
    int mrow = m0 + wid * 16 + rn;
    int mclamp = mrow < M ? mrow : M - 1;
    const u16* aptr = A + (size_t)mclamp * K + kq;
    floatx4 acc0 = {0.f,0.f,0.f,0.f}, acc1 = acc0, acc2 = acc0, acc3 = acc0;
    for (int kt = 0; kt < K; kt += 32) {
        short8 a  = *(const short8*)(const void*)(aptr + kt);
        short8 b0 = *(const short8*)(const void*)(lbt + ( 0 + rn) * KP + kq + kt);
        short8 b1 = *(const short8*)(const void*)(lbt + (16 + rn) * KP + kq + kt);
        short8 b2 = *(const short8*)(const void*)(lbt + (32 + rn) * KP + kq + kt);
        short8 b3 = *(const short8*)(const void*)(lbt + (48 + rn) * KP + kq + kt);
        acc0 = __builtin_amdgcn_mfma_f32_16x16x32_bf16(a, b0, acc0, 0, 0, 0);
        acc1 = __builtin_amdgcn_mfma_f32_16x16x32_bf16(a, b1, acc1, 0, 0, 0);
        acc2 = __builtin_amdgcn_mfma_f32_16x16x32_bf16(a, b2, acc2, 0, 0, 0);
        acc3 = __builtin_amdgcn_mfma_f32_16x16x32_bf16(a, b3, acc3, 0, 0, 0);
    }
    int rbase = m0 + wid * 16 + (lane >> 4) * 4;   // C/D: col=lane&15, row=(lane>>4)*4+i
    floatx4 accs[4] = {acc0, acc1, acc2, acc3};
    for (int j = 0; j < 4; ++j) {
        int col = n0 + j * 16 + rn;
        float bs = bias[col];
        for (int i = 0; i < 4; ++i) {
            int row = rbase + i;
            if (row < M) {
                float rs = rowscale ? rowscale[row] : 1.0f;
                float v = accs[j][i] + rs * bs;
                if (relu) v = v < 0.f ? 0.f : v;   // NaN-propagating
                C[(size_t)row * N + col] = f2bf(v);
            }
        }
    }
}

// ---------------- aggregation (NF=128): 4 rows/wave, 16 lanes/row, uint4 gathers ----------------
__device__ inline void accum8(float* acc, uint4 r, float v) {
    acc[0] += v * bf2f((u16)(r.x & 0xffffu)); acc[1] += v * bf2f((u16)(r.x >> 16));
    acc[2] += v * bf2f((u16)(r.y & 0xffffu)); acc[3] += v * bf2f((u16)(r.y >> 16));
    acc[4] += v * bf2f((u16)(r.z & 0xffffu)); acc[5] += v * bf2f((u16)(r.z >> 16));
    acc[6] += v * bf2f((u16)(r.w & 0xffffu)); acc[7] += v * bf2f((u16)(r.w >> 16));
}

__global__ __launch_bounds__(256) void k_agg(const u16* __restrict__ t,
                                             const int* __restrict__ row_ptr,
                                             const uint2* __restrict__ edges,
                                             u16* __restrict__ agg,
                                             float* __restrict__ rowsum) {
    int tid = threadIdx.x;
    int lane = tid & 63;
    int sub = lane >> 4;                 // row slot within wave (0..3)
    int l16 = lane & 15;                 // feature-lane within row
    int row = blockIdx.x * 16 + (tid >> 6) * 4 + sub;   // 150000/16 = 9375 blocks exact
    float acc[8] = {0.f,0.f,0.f,0.f,0.f,0.f,0.f,0.f};
    float sv = 0.f;
    int s = row_ptr[row], e = row_ptr[row + 1];
    const u16* tf = t + l16 * 8;
    int i = s;
    for (; i + 4 <= e; i += 4) {
        uint2 e0 = edges[i], e1 = edges[i+1], e2 = edges[i+2], e3 = edges[i+3];
        uint4 r0 = *(const uint4*)(const void*)(tf + (size_t)e0.x * 128);
        uint4 r1 = *(const uint4*)(const void*)(tf + (size_t)e1.x * 128);
        uint4 r2 = *(const uint4*)(const void*)(tf + (size_t)e2.x * 128);
        uint4 r3 = *(const uint4*)(const void*)(tf + (size_t)e3.x * 128);
        float v0 = itof(e0.y), v1 = itof(e1.y), v2 = itof(e2.y), v3 = itof(e3.y);
        accum8(acc, r0, v0); accum8(acc, r1, v1);
        accum8(acc, r2, v2); accum8(acc, r3, v3);
        sv += v0 + v1 + v2 + v3;
    }
    for (; i < e; ++i) {
        uint2 e0 = edges[i];
        uint4 r0 = *(const uint4*)(const void*)(tf + (size_t)e0.x * 128);
        float v0 = itof(e0.y);
        accum8(acc, r0, v0);
        sv += v0;
    }
    uint4 w;
    w.x = pack2(acc[0], acc[1]); w.y = pack2(acc[2], acc[3]);
    w.z = pack2(acc[4], acc[5]); w.w = pack2(acc[6], acc[7]);
    *(uint4*)(void*)(agg + (size_t)row * 128 + l16 * 8) = w;
    if (rowsum != nullptr && l16 == 0) rowsum[row] = sv;
}

// ---------------- BatchNorm stats ----------------
__global__ __launch_bounds__(256) void k_bnstats(const u16* __restrict__ agg,
                                                 float* __restrict__ stats, int NF) {
    int tid = threadIdx.x;
    int rpb = 256 / NF;
    int f = tid & (NF - 1);
    int r0 = blockIdx.x * rpb + tid / NF;
    int rs = gridDim.x * rpb;
    float s = 0.f, s2 = 0.f;
    for (int row = r0; row < N_NODES; row += rs) {
        float v = bf2f(agg[(size_t)row * NF + f]);
        s += v; s2 += v * v;
    }
    atomicAdd(&stats[f], s);
    atomicAdd(&stats[NF + f], s2);
}

// ---------------- BatchNorm apply + ReLU -> bf16 ----------------
__global__ __launch_bounds__(256) void k_bnapply(const u16* __restrict__ agg,
                                                 const float* __restrict__ stats,
                                                 const float* __restrict__ g,
                                                 const float* __restrict__ beta,
                                                 u16* __restrict__ x, int NF) {
    size_t idx = (size_t)blockIdx.x * 256 + threadIdx.x;
    if (idx >= (size_t)N_NODES * NF) return;
    int f = (int)(idx & (size_t)(NF - 1));
    float mu = stats[f] * (1.0f / N_NODES);
    float var = stats[NF + f] * (1.0f / N_NODES) - mu * mu;
    float sc = rsqrtf(var + EPSV) * g[f];
    float v = (bf2f(agg[idx]) - mu) * sc + beta[f];
    x[idx] = f2bf(v < 0.f ? 0.f : v);
}

// ---------------- gather u||v with fused BN2+ReLU -> comb [B,256] bf16 ----------------
__global__ __launch_bounds__(256) void k_gatherBN(const int* __restrict__ ui,
                                                  const int* __restrict__ ii,
                                                  const u16* __restrict__ agg2,
                                                  const float* __restrict__ stats,
                                                  const float* __restrict__ g,
                                                  const float* __restrict__ beta,
                                                  u16* __restrict__ comb) {
    int item = blockIdx.x * 4 + (threadIdx.x >> 6);
    int lane = threadIdx.x & 63;
    if (item >= BATCH) return;
    int node = (lane < 32) ? ui[item] : (N_USERS + ii[item]);
    int fb = (lane & 31) * 4;
    uint2 r = *(const uint2*)(const void*)(agg2 + (size_t)node * H2 + fb);
    float vv[4] = { bf2f((u16)(r.x & 0xffffu)), bf2f((u16)(r.x >> 16)),
                    bf2f((u16)(r.y & 0xffffu)), bf2f((u16)(r.y >> 16)) };
    u16 o[4];
    for (int j = 0; j < 4; ++j) {
        int f = fb + j;
        float mu = stats[f] * (1.0f / N_NODES);
        float var = stats[H2 + f] * (1.0f / N_NODES) - mu * mu;
        float sc = rsqrtf(var + EPSV) * g[f];
        float v = (vv[j] - mu) * sc + beta[f];
        o[j] = f2bf(v < 0.f ? 0.f : v);
    }
    uint2 w;
    w.x = (uint32_t)o[0] | ((uint32_t)o[1] << 16);
    w.y = (uint32_t)o[2] | ((uint32_t)o[3] << 16);
    *(uint2*)(void*)(comb + (size_t)item * (2 * H2) + lane * 4) = w;
}

// ---------------- final dot ----------------
__global__ __launch_bounds__(256) void k_final(const u16* __restrict__ h,
                                               const float* __restrict__ P2,
                                               const float* __restrict__ pb2,
                                               float* __restrict__ out) {
    int item = blockIdx.x * 4 + (threadIdx.x >> 6);
    int lane = threadIdx.x & 63;
    if (item >= BATCH) return;
    float a = bf2f(h[(size_t)item * H2 + lane])      * P2[lane]
            + bf2f(h[(size_t)item * H2 + 64 + lane]) * P2[64 + lane];
    for (int off = 32; off > 0; off >>= 1) a += __shfl_down(a, off, 64);
    if (lane == 0) out[item] = a + pb2[0];
}

extern "C" void kernel_launch(void* const* d_in, const int* in_sizes, int n_in,
                              void* d_out, int out_size, void* d_ws, size_t ws_size,
                              hipStream_t stream) {
    (void)in_sizes; (void)n_in; (void)ws_size;
    const int* user_indices = (const int*)d_in[0];
    const int* item_indices = (const int*)d_in[1];
    const int* edge_rows    = (const int*)d_in[2];
    const int* edge_cols    = (const int*)d_in[3];
    const float* edge_vals = (const float*)d_in[4];
    const float* user_emb  = (const float*)d_in[5];
    const float* item_emb  = (const float*)d_in[6];
    const float* W1    = (const float*)d_in[7];
    const float* b1    = (const float*)d_in[8];
    const float* g1    = (const float*)d_in[9];
    const float* beta1 = (const float*)d_in[10];
    const float* W2    = (const float*)d_in[11];
    const float* b2    = (const float*)d_in[12];
    const float* g2    = (const float*)d_in[13];
    const float* beta2 = (const float*)d_in[14];
    const float* P1    = (const float*)d_in[15];
    const float* pb1   = (const float*)d_in[16];
    const float* P2    = (const float*)d_in[17];
    const float* pb2   = (const float*)d_in[18];
    float* out = (float*)d_out;

    // workspace layout (~195 MB)
    char* ws = (char*)d_ws;
    size_t off = 0;
    auto alloc = [&](size_t bytes) -> char* {
        char* p = ws + off;
        off = (off + bytes + 255) & ~(size_t)255;
        return p;
    };
    int*   row_ptr  = (int*)alloc(sizeof(int) * (N_NODES + 1));
    int*   bcount   = (int*)alloc(sizeof(int) * (NBUCK + 1));
    int*   bbase    = (int*)alloc(sizeof(int) * (NBUCK + 1));
    int*   bcursor  = (int*)alloc(sizeof(int) * (NBUCK + 1));
    float* rowsum   = (float*)alloc(sizeof(float) * N_NODES);
    float* stats1   = (float*)alloc(sizeof(float) * 2 * H1);
    float* stats2   = (float*)alloc(sizeof(float) * 2 * H2);
    u16* WT1 = (u16*)alloc(2 * D0 * H1);
    u16* WT2 = (u16*)alloc(2 * H1 * H2);
    u16* PT1 = (u16*)alloc(2 * 2 * H2 * H2);
    uint2* efin = (uint2*)alloc(8 * (size_t)NEDGE);     // final CSR edges
    // R1 (76.8 MB): xb | aggx, later x1 (full)
    u16* R1   = (u16*)alloc(2 * (size_t)N_NODES * H1);
    u16* xb   = R1;
    u16* aggx = R1 + (size_t)N_NODES * D0;
    u16* x1   = R1;
    // R2 (76.8 MB): etmp (sort scratch) -> agg1 -> {t2 | agg2} -> {comb+hbuf | agg2}
    u16* R2   = (u16*)alloc(2 * (size_t)N_NODES * H1);
    uint2* etmp = (uint2*)R2;                            // 38.4 MB, dead after k_place2
    u16* agg1 = R2;
    u16* t2   = R2;
    u16* agg2 = R2 + (size_t)N_NODES * H2;
    u16* comb = R2;
    u16* hbuf = R2 + (size_t)BATCH * 2 * H2;

    // fused init (canary 2.0 + zero bcount/stats)
    k_init<<<(out_size + 255) / 256, 256, 0, stream>>>(out, out_size, bcount, stats1, stats2);

    // x -> bf16
    k_cvt<<<(N_NODES * D0 / 4 + 255) / 256, 256, 0, stream>>>(user_emb, item_emb, xb);

    // CSR build: bucket-count -> scan(147) -> bucket stage -> place (+row_ptr)
    k_bcount<<<(NEDGE + CCHUNK - 1) / CCHUNK, 256, 0, stream>>>(edge_rows, bcount);
    k_bscan<<<1, 256, 0, stream>>>(bcount, bbase, bcursor, row_ptr);
    k_bucket<<<(NEDGE + BCHUNK - 1) / BCHUNK, 256, 0, stream>>>(
        edge_rows, edge_cols, edge_vals, bcursor, etmp);
    k_place2<<<NBUCK, 1024, 0, stream>>>(bbase, etmp, row_ptr, efin);

    // fused weight transposes fp32 -> bf16 (B^T layout)
    k_transpose3<<<(3 * 32768) / 256, 256, 0, stream>>>(W1, W2, P1, WT1, WT2, PT1);

    // layer 1 (agg-then-GEMM via linearity): aggx = agg(xb); agg1 = aggx@W1 + s_r*b1
    k_agg<<<N_NODES / 16, 256, 0, stream>>>(xb, row_ptr, efin, aggx, rowsum);
    k_gemm<<<dim3((N_NODES + 63) / 64, H1 / 64), 256, 0, stream>>>(
        aggx, N_NODES, D0, WT1, b1, rowsum, agg1, H1, 0);
    k_bnstats<<<512, 256, 0, stream>>>(agg1, stats1, H1);
    k_bnapply<<<(N_NODES * H1) / 256, 256, 0, stream>>>(agg1, stats1, g1, beta1, x1, H1);

    // layer 2 (GEMM-then-agg): t2 = x1@W2 + b2 ; agg2 = agg(t2)
    k_gemm<<<dim3((N_NODES + 63) / 64, H2 / 64), 256, 0, stream>>>(
        x1, N_NODES, H1, WT2, b2, nullptr, t2, H2, 0);
    k_agg<<<N_NODES / 16, 256, 0, stream>>>(t2, row_ptr, efin, agg2, nullptr);
    k_bnstats<<<512, 256, 0, stream>>>(agg2, stats2, H2);

    // head: gather with fused BN2+ReLU, MLP, dot
    k_gatherBN<<<BATCH / 4, 256, 0, stream>>>(user_indices, item_indices, agg2,
                                              stats2, g2, beta2, comb);
    k_gemm<<<dim3(BATCH / 64, H2 / 64), 256, 0, stream>>>(
        comb, BATCH, 2 * H2, PT1, pb1, nullptr, hbuf, H2, 1);
    k_final<<<BATCH / 4, 256, 0, stream>>>(hbuf, P2, pb2, out);
}